// Round 9
// baseline (4776.487 us; speedup 1.0000x reference)
//
#include <hip/hip_runtime.h>
#include <math.h>

#define N_PTS 8192
#define BATCH 2
#define M_CTR 2048
#define KNB   32
#define CIN   64
#define CH    128
#define NHEAD 8
#define DH    16
#define FPSB  4     // FPS blocks per batch

typedef __attribute__((ext_vector_type(4))) float f32x4;
typedef __attribute__((ext_vector_type(8))) short bf16x8;

// ---------------------------------------------------------------------------
// FPS v8: 4 blocks per batch, 512 thr each, 4 pts/thread in registers.
// Exact f32 distances (no FMA contraction). u64 key (bits(mind)<<32)|~idx ==
// (value desc, global idx asc) -> exact numpy first-index argmax in any
// reduction order. Per-block: per-thread tree + DPP butterfly
// (xor1/xor2/xor7/xor15 + swz16 + shfl32, HW-verified R5) + 8-slot LDS tree.
// Cross-block: parity-buffered candG + monotone tagG, release/acquire AGENT
// atomics (device scope; blocks stay within 1 iteration -> parity buffer is
// race-free). Tags zeroed by init_sync each launch (prior-launch tags = 2048
// and 0xAA poison would otherwise satisfy polls). 8 blocks << 256 CUs ->
// co-residency guaranteed, spin-wait safe.
// ---------------------------------------------------------------------------
template<int CTRL>
__device__ __forceinline__ unsigned long long dpp_max_u64(unsigned long long k) {
  int lo = (int)(unsigned)k;
  int hi = (int)(k >> 32);
  int lo2 = __builtin_amdgcn_update_dpp(0, lo, CTRL, 0xF, 0xF, true);
  int hi2 = __builtin_amdgcn_update_dpp(0, hi, CTRL, 0xF, 0xF, true);
  unsigned long long o = ((unsigned long long)(unsigned)hi2 << 32) | (unsigned)lo2;
  return o > k ? o : k;
}
__device__ __forceinline__ unsigned long long swz16_max_u64(unsigned long long k) {
  int lo = (int)(unsigned)k;
  int hi = (int)(k >> 32);
  int lo2 = __builtin_amdgcn_ds_swizzle(lo, 0x401F);   // xor 16
  int hi2 = __builtin_amdgcn_ds_swizzle(hi, 0x401F);
  unsigned long long o = ((unsigned long long)(unsigned)hi2 << 32) | (unsigned)lo2;
  return o > k ? o : k;
}
__device__ __forceinline__ unsigned long long maxu64(unsigned long long a,
                                                     unsigned long long b) {
  return a > b ? a : b;
}

__global__ void init_sync(unsigned* __restrict__ tagG) {
  if (threadIdx.x < BATCH * FPSB) tagG[threadIdx.x] = 0u;
}

__global__ __launch_bounds__(512, 1) void fps_kernel(const float* __restrict__ xyz,
                                                     int* __restrict__ ctrIdx,
                                                     float* __restrict__ outCtr,
                                                     unsigned long long* __restrict__ candG,
                                                     unsigned* __restrict__ tagG) {
  __shared__ float4 sxyz[N_PTS];                    // 128 KB (full batch copy)
  __shared__ __align__(16) unsigned long long candK[8];
  __shared__ unsigned long long remC[3];

  const int gb  = blockIdx.x;
  const int b   = gb >> 2;
  const int blk = gb & 3;
  const int t = threadIdx.x;
  const int lane = t & 63;
  const int w = t >> 6;
  const float* xb = xyz + (size_t)b * N_PTS * 3;

  // full-batch coords into LDS (one-time)
  for (int i = t; i < N_PTS; i += 512)
    sxyz[i] = make_float4(xb[i * 3 + 0], xb[i * 3 + 1], xb[i * 3 + 2], 0.f);

  // own 2048 points in registers
  float px[4], py[4], pz[4], mind[4];
  unsigned lo4[4];
#pragma unroll
  for (int s = 0; s < 4; ++s) {
    int pt = blk * 2048 + s * 512 + t;
    px[s] = xb[pt * 3 + 0];
    py[s] = xb[pt * 3 + 1];
    pz[s] = xb[pt * 3 + 2];
    mind[s] = INFINITY;
    lo4[s] = ~(unsigned)pt;
  }
  __syncthreads();

  unsigned long long* myCand0 = candG + (size_t)(b * 2 + 0) * FPSB;
  unsigned long long* myCand1 = candG + (size_t)(b * 2 + 1) * FPSB;
  unsigned* myTag = tagG + b * FPSB;

  int last = 0;
  for (int m = 0; m < M_CTR; ++m) {
    float4 lp = sxyz[last];                          // uniform broadcast
    if (blk == 0 && t == 0) {
      ctrIdx[b * M_CTR + m] = last;
      float* o = outCtr + (size_t)(b * M_CTR + m) * 3;
      o[0] = lp.x; o[1] = lp.y; o[2] = lp.z;
    }
    unsigned long long key[4];
#pragma unroll
    for (int s = 0; s < 4; ++s) {
      float dx = __fsub_rn(px[s], lp.x);
      float dy = __fsub_rn(py[s], lp.y);
      float dz = __fsub_rn(pz[s], lp.z);
      float d2 = __fadd_rn(__fadd_rn(__fmul_rn(dx, dx), __fmul_rn(dy, dy)),
                           __fmul_rn(dz, dz));
      float mn = fminf(mind[s], d2);
      mind[s] = mn;
      key[s] = ((unsigned long long)__float_as_uint(mn) << 32) | lo4[s];
    }
    key[0] = maxu64(key[0], key[2]);
    key[1] = maxu64(key[1], key[3]);
    unsigned long long k0 = maxu64(key[0], key[1]);
    k0 = dpp_max_u64<0xB1>(k0);     // quad_perm xor1
    k0 = dpp_max_u64<0x4E>(k0);     // quad_perm xor2
    k0 = dpp_max_u64<0x141>(k0);    // row_half_mirror (xor7)
    k0 = dpp_max_u64<0x140>(k0);    // row_mirror (xor15)
    k0 = swz16_max_u64(k0);         // xor16
    k0 = maxu64(k0, (unsigned long long)__shfl_xor((unsigned long long)k0, 32, 64));
    if (lane == 0) candK[w] = k0;
    __syncthreads();                 // B1: candK ready (single-buffer OK: 2 barriers/iter)
    const ulonglong2* ck = (const ulonglong2*)&candK[0];
    ulonglong2 c0v = ck[0], c1v = ck[1], c2v = ck[2], c3v = ck[3];
    unsigned long long m0 = maxu64(c0v.x, c0v.y);
    unsigned long long m1 = maxu64(c1v.x, c1v.y);
    unsigned long long m2 = maxu64(c2v.x, c2v.y);
    unsigned long long m3 = maxu64(c3v.x, c3v.y);
    unsigned long long blockBest = maxu64(maxu64(m0, m1), maxu64(m2, m3));
    // cross-block exchange
    unsigned long long* candPar = (m & 1) ? myCand1 : myCand0;
    if (t == 0) {
      __hip_atomic_store(&candPar[blk], blockBest, __ATOMIC_RELAXED,
                         __HIP_MEMORY_SCOPE_AGENT);
      __hip_atomic_store(&myTag[blk], (unsigned)(m + 1), __ATOMIC_RELEASE,
                         __HIP_MEMORY_SCOPE_AGENT);
    }
    if (t < 3) {
      int j = (blk + 1 + t) & 3;
      while (__hip_atomic_load(&myTag[j], __ATOMIC_ACQUIRE,
                               __HIP_MEMORY_SCOPE_AGENT) < (unsigned)(m + 1)) {}
      remC[t] = __hip_atomic_load(&candPar[j], __ATOMIC_RELAXED,
                                  __HIP_MEMORY_SCOPE_AGENT);
    }
    __syncthreads();                 // B2: remC ready
    unsigned long long best = maxu64(maxu64(blockBest, remC[0]),
                                     maxu64(remC[1], remC[2]));
    last = (int)(~(unsigned)best);
  }
}

// ---------------------------------------------------------------------------
// Ball query (unchanged).
// ---------------------------------------------------------------------------
__global__ __launch_bounds__(256) void ballq_kernel(const float* __restrict__ xyz,
                                                    const int* __restrict__ ctrIdx,
                                                    int* __restrict__ rawIdx) {
  const int cm   = blockIdx.x * 4 + (threadIdx.x >> 6);
  const int lane = threadIdx.x & 63;
  const int b    = cm >> 11;
  const float* xb = xyz + (size_t)b * N_PTS * 3;
  const int ci = ctrIdx[cm];
  const float cx = xb[ci * 3 + 0], cy = xb[ci * 3 + 1], cz = xb[ci * 3 + 2];
  int* out = rawIdx + (size_t)cm * KNB;
  int have = 0;
  for (int base = 0; base < N_PTS; base += 64) {
    int pt = base + lane;
    float dx = __fsub_rn(cx, xb[pt * 3 + 0]);
    float dy = __fsub_rn(cy, xb[pt * 3 + 1]);
    float dz = __fsub_rn(cz, xb[pt * 3 + 2]);
    float d2 = __fadd_rn(__fadd_rn(__fmul_rn(dx, dx), __fmul_rn(dy, dy)),
                         __fmul_rn(dz, dz));
    bool hit = d2 < 0.25f;
    unsigned long long mask = __ballot(hit);
    if (hit) {
      int rank = have + __popcll(mask & ((1ull << lane) - 1ull));
      if (rank < KNB) out[rank] = pt;
    }
    have += __popcll(mask);
    if (have >= KNB) break;
  }
  if (lane < KNB && lane >= have) out[lane] = -1;
}

// ---------------------------------------------------------------------------
// Weight prep (unchanged): bf16 transposed weights Wt[c][k] in workspace.
// ---------------------------------------------------------------------------
__device__ __forceinline__ unsigned short f2bf(float f) {
  unsigned u = __float_as_uint(f);
  unsigned r = (u + 0x7FFFu + ((u >> 16) & 1u)) >> 16;   // RNE
  return (unsigned short)r;
}
__device__ __forceinline__ float bf2f(unsigned short s) {
  return __uint_as_float(((unsigned)s) << 16);
}

__global__ __launch_bounds__(256) void prep_kernel(const float* __restrict__ W_in,
    const float* __restrict__ Wq, const float* __restrict__ Wk,
    const float* __restrict__ Wv, const float* __restrict__ Wo,
    const float* __restrict__ W1, const float* __restrict__ W2,
    short* __restrict__ wsW) {
  int i = blockIdx.x * 256 + threadIdx.x;
  if (i >= 204800) return;
  const float* src; int K, C, off;
  if (i < 8192)        { src = W_in; K = 64;  C = 128; off = i; }
  else if (i < 24576)  { src = Wq;   K = 128; C = 128; off = i - 8192; }
  else if (i < 40960)  { src = Wk;   K = 128; C = 128; off = i - 24576; }
  else if (i < 57344)  { src = Wv;   K = 128; C = 128; off = i - 40960; }
  else if (i < 73728)  { src = Wo;   K = 128; C = 128; off = i - 57344; }
  else if (i < 139264) { src = W1;   K = 128; C = 512; off = i - 73728; }
  else                 { src = W2;   K = 512; C = 128; off = i - 139264; }
  int c = off / K, k = off - c * K;
  wsW[i] = (short)f2bf(src[(size_t)k * C + c]);
}

// ---------------------------------------------------------------------------
// Fused per-center transformer v3 (unchanged from passing R6): MFMA bf16,
// 128 thr = 2 waves per center.
// ---------------------------------------------------------------------------
#define XS  136   // activation LDS row stride (shorts)
#define VTS 40    // vT row stride
#define PS  264   // P row stride

struct SAParams {
  const float* xyz; const float* feats;
  const float* b_in; const float* ln_in_g; const float* ln_in_b;
  const float* W_pos; const float* b_pos;
  const float* bq; const float* bk; const float* bv; const float* bo;
  const float* ln1_g; const float* ln1_b;
  const float* b1; const float* b2;
  const float* ln2_g; const float* ln2_b; const float* out_g; const float* out_b;
  const short* wsW;
  const int* ctrIdx; const int* rawIdx;
  float* out;
};

template<int C>
__device__ __forceinline__ float dppf(float v) {
  return __int_as_float(__builtin_amdgcn_update_dpp(0, __float_as_int(v), C, 0xF, 0xF, true));
}
__device__ __forceinline__ float red16_add(float v) {
  v += dppf<0xB1>(v);  v += dppf<0x4E>(v);
  v += dppf<0x141>(v); v += dppf<0x140>(v);
  return v;
}
__device__ __forceinline__ float red16_max(float v) {
  v = fmaxf(v, dppf<0xB1>(v));  v = fmaxf(v, dppf<0x4E>(v));
  v = fmaxf(v, dppf<0x141>(v)); v = fmaxf(v, dppf<0x140>(v));
  return v;
}

template<int NCT, int NKS>
__device__ __forceinline__ void mm_mfma(const short* __restrict__ albase, int lstr,
                                        const short* __restrict__ wt, int wK,
                                        f32x4 (&acc)[NCT], int l15, int lg) {
#pragma unroll
  for (int ks = 0; ks < NKS; ++ks) {
    bf16x8 a = *(const bf16x8*)(albase + l15 * lstr + ks * 32 + lg * 8);
#pragma unroll
    for (int ct = 0; ct < NCT; ++ct) {
      bf16x8 bf = *(const bf16x8*)(wt + (size_t)(ct * 16 + l15) * wK + ks * 32 + lg * 8);
      acc[ct] = __builtin_amdgcn_mfma_f32_16x16x32_bf16(a, bf, acc[ct], 0, 0, 0);
    }
  }
}

__global__ __launch_bounds__(128, 1) void sa_kernel(SAParams p) {
  __shared__ short sm[3 * 32 * XS + 128 * VTS + 32 * PS];
  __shared__ float nxs[32], nys[32], nzs[32];
  __shared__ int   nidx[32];
  __shared__ unsigned padmaskS;
  __shared__ float psum[2][2];

  short* const xb  = sm;
  short* const qb  = sm + 32 * XS;
  short* const kb  = sm + 2 * 32 * XS;
  short* const vT  = sm + 3 * 32 * XS;
  short* const Pb  = sm + 3 * 32 * XS + 128 * VTS;
  short* const fsb = Pb;
  short* const ob  = qb;
  short* const hb  = kb;

  const int t    = threadIdx.x;
  const int lane = t & 63;
  const int rt   = t >> 6;
  const int l15  = lane & 15;
  const int lg   = lane >> 4;
  const int cm   = blockIdx.x;
  const int b    = cm >> 11;
  const short* arow = 0;

  if (t < 32) {
    int raw = p.rawIdx[(size_t)cm * KNB + t];
    int ci  = p.ctrIdx[cm];
    int ni  = (raw < 0) ? ci : raw;
    nidx[t] = ni;
    const float* q = p.xyz + ((size_t)b * N_PTS + ni) * 3;
    nxs[t] = q[0]; nys[t] = q[1]; nzs[t] = q[2];
  }
  if (t < 64) {
    bool isPad = (t < 32) ? (p.rawIdx[(size_t)cm * KNB + t] < 0) : false;
    unsigned long long m = __ballot(isPad);
    if (t == 0) padmaskS = (unsigned)m;
  }
  __syncthreads();

  {
    int row = t >> 2;
    int cs  = (t & 3) * 16;
    const float* src = p.feats + ((size_t)b * N_PTS + nidx[row]) * CIN + cs;
    float4 f0 = *(const float4*)(src + 0);
    float4 f1 = *(const float4*)(src + 4);
    float4 f2 = *(const float4*)(src + 8);
    float4 f3 = *(const float4*)(src + 12);
    unsigned short u[16];
#pragma unroll
    for (int j = 0; j < 4; ++j) {
      u[j]      = f2bf((&f0.x)[j]); u[4 + j]  = f2bf((&f1.x)[j]);
      u[8 + j]  = f2bf((&f2.x)[j]); u[12 + j] = f2bf((&f3.x)[j]);
    }
    unsigned packed[8];
#pragma unroll
    for (int j = 0; j < 8; ++j) packed[j] = (unsigned)u[2 * j] | ((unsigned)u[2 * j + 1] << 16);
    uint4 w0 = make_uint4(packed[0], packed[1], packed[2], packed[3]);
    uint4 w1 = make_uint4(packed[4], packed[5], packed[6], packed[7]);
    *(uint4*)(fsb + row * 72 + cs)     = w0;
    *(uint4*)(fsb + row * 72 + cs + 8) = w1;
  }
  __syncthreads();

  const unsigned padmask = padmaskS;
  float rowxyz[3][4];
#pragma unroll
  for (int r = 0; r < 4; ++r) {
    int row = rt * 16 + lg * 4 + r;
    rowxyz[0][r] = nxs[row]; rowxyz[1][r] = nys[row]; rowxyz[2][r] = nzs[row];
  }

  // ---- in-proj + LN + relu + posenc -> xb ----
  {
    f32x4 acc[8] = {};
    mm_mfma<8, 2>(fsb + rt * 16 * 72, 72, p.wsW + 0, 64, acc, l15, lg);
    float s[4] = {}, sq[4] = {};
#pragma unroll
    for (int ct = 0; ct < 8; ++ct) {
      float bia = p.b_in[ct * 16 + l15];
#pragma unroll
      for (int r = 0; r < 4; ++r) {
        acc[ct][r] += bia;
        s[r] += acc[ct][r]; sq[r] += acc[ct][r] * acc[ct][r];
      }
    }
    float mean[4], inv[4];
#pragma unroll
    for (int r = 0; r < 4; ++r) {
      float S = red16_add(s[r]), SQ = red16_add(sq[r]);
      mean[r] = S * (1.0f / CH);
      float var = fmaxf(SQ * (1.0f / CH) - mean[r] * mean[r], 0.f);
      inv[r] = rsqrtf(var + 1e-5f);
    }
#pragma unroll
    for (int ct = 0; ct < 8; ++ct) {
      int c = ct * 16 + l15;
      float g  = p.ln_in_g[c], bt = p.ln_in_b[c];
      float w0 = p.W_pos[0 * CH + c], w1 = p.W_pos[1 * CH + c];
      float w2 = p.W_pos[2 * CH + c], bp = p.b_pos[c];
#pragma unroll
      for (int r = 0; r < 4; ++r) {
        int row = rt * 16 + lg * 4 + r;
        float h = (acc[ct][r] - mean[r]) * inv[r] * g + bt;
        h = fmaxf(h, 0.f);
        float pos = fmaf(rowxyz[0][r], w0, fmaf(rowxyz[1][r], w1,
                    fmaf(rowxyz[2][r], w2, bp)));
        xb[row * XS + c] = (short)f2bf(h + pos);
      }
    }
  }
  __syncthreads();

  // ---- q, k, v ----
  arow = xb + rt * 16 * XS;
  {
    f32x4 acc[8] = {};
    mm_mfma<8, 4>(arow, XS, p.wsW + 8192, 128, acc, l15, lg);
#pragma unroll
    for (int ct = 0; ct < 8; ++ct) {
      int c = ct * 16 + l15;
      float bia = p.bq[c];
#pragma unroll
      for (int r = 0; r < 4; ++r)
        qb[(rt * 16 + lg * 4 + r) * XS + c] = (short)f2bf((acc[ct][r] + bia) * 0.25f);
    }
  }
  {
    f32x4 acc[8] = {};
    mm_mfma<8, 4>(arow, XS, p.wsW + 24576, 128, acc, l15, lg);
#pragma unroll
    for (int ct = 0; ct < 8; ++ct) {
      int c = ct * 16 + l15;
      float bia = p.bk[c];
#pragma unroll
      for (int r = 0; r < 4; ++r)
        kb[(rt * 16 + lg * 4 + r) * XS + c] = (short)f2bf(acc[ct][r] + bia);
    }
  }
  {
    f32x4 acc[8] = {};
    mm_mfma<8, 4>(arow, XS, p.wsW + 40960, 128, acc, l15, lg);
#pragma unroll
    for (int ct = 0; ct < 8; ++ct) {
      int c = ct * 16 + l15;
      float bia = p.bv[c];
#pragma unroll
      for (int r = 0; r < 4; ++r)
        vT[c * VTS + rt * 16 + lg * 4 + r] = (short)f2bf(acc[ct][r] + bia);
    }
  }
  __syncthreads();

  // ---- scores + softmax -> Pb ----
  {
    bool pad0 = (padmask >> l15) & 1u;
    bool pad1 = (padmask >> (16 + l15)) & 1u;
    const bf16x8 z = {0, 0, 0, 0, 0, 0, 0, 0};
#pragma unroll
    for (int h = 0; h < NHEAD; ++h) {
      bf16x8 a = *(const bf16x8*)(qb + (rt * 16 + l15) * XS + h * DH + (lg & 1) * 8);
      if (lg >= 2) a = z;
      bf16x8 b0 = *(const bf16x8*)(kb + (l15) * XS + h * DH + (lg & 1) * 8);
      bf16x8 b1 = *(const bf16x8*)(kb + (16 + l15) * XS + h * DH + (lg & 1) * 8);
      f32x4 s0 = {}, s1 = {};
      s0 = __builtin_amdgcn_mfma_f32_16x16x32_bf16(a, b0, s0, 0, 0, 0);
      s1 = __builtin_amdgcn_mfma_f32_16x16x32_bf16(a, b1, s1, 0, 0, 0);
#pragma unroll
      for (int r = 0; r < 4; ++r) {
        float v0 = pad0 ? -1e9f : s0[r];
        float v1 = pad1 ? -1e9f : s1[r];
        float mx = red16_max(fmaxf(v0, v1));
        float e0 = __expf(v0 - mx), e1 = __expf(v1 - mx);
        float sum = red16_add(e0 + e1);
        float isum = 1.0f / sum;
        int row = rt * 16 + lg * 4 + r;
        Pb[row * PS + h * 32 + l15]      = (short)f2bf(e0 * isum);
        Pb[row * PS + h * 32 + 16 + l15] = (short)f2bf(e1 * isum);
      }
    }
  }
  __syncthreads();

  // ---- PV -> ob ----
  {
#pragma unroll
    for (int h = 0; h < NHEAD; ++h) {
      bf16x8 a  = *(const bf16x8*)(Pb + (rt * 16 + l15) * PS + h * 32 + lg * 8);
      bf16x8 bf = *(const bf16x8*)(vT + (h * DH + l15) * VTS + lg * 8);
      f32x4 o = {};
      o = __builtin_amdgcn_mfma_f32_16x16x32_bf16(a, bf, o, 0, 0, 0);
#pragma unroll
      for (int r = 0; r < 4; ++r)
        ob[(rt * 16 + lg * 4 + r) * XS + h * DH + l15] = (short)f2bf(o[r]);
    }
  }

  // ---- x = LN1(x + o@Wo + bo) ----
  {
    f32x4 acc[8] = {};
    mm_mfma<8, 4>(ob + rt * 16 * XS, XS, p.wsW + 57344, 128, acc, l15, lg);
    float s[4] = {}, sq[4] = {};
#pragma unroll
    for (int ct = 0; ct < 8; ++ct) {
      int c = ct * 16 + l15;
      float bia = p.bo[c];
#pragma unroll
      for (int r = 0; r < 4; ++r) {
        int row = rt * 16 + lg * 4 + r;
        acc[ct][r] += bia + bf2f((unsigned short)xb[row * XS + c]);
        s[r] += acc[ct][r]; sq[r] += acc[ct][r] * acc[ct][r];
      }
    }
    float mean[4], inv[4];
#pragma unroll
    for (int r = 0; r < 4; ++r) {
      float S = red16_add(s[r]), SQ = red16_add(sq[r]);
      mean[r] = S * (1.0f / CH);
      float var = fmaxf(SQ * (1.0f / CH) - mean[r] * mean[r], 0.f);
      inv[r] = rsqrtf(var + 1e-5f);
    }
#pragma unroll
    for (int ct = 0; ct < 8; ++ct) {
      int c = ct * 16 + l15;
      float g = p.ln1_g[c], bt = p.ln1_b[c];
#pragma unroll
      for (int r = 0; r < 4; ++r) {
        int row = rt * 16 + lg * 4 + r;
        xb[row * XS + c] = (short)f2bf((acc[ct][r] - mean[r]) * inv[r] * g + bt);
      }
    }
  }

  // ---- FFN + LN2 ----
  {
    f32x4 acc2[8] = {};
#pragma unroll
    for (int cb = 0; cb < 4; ++cb) {
      f32x4 acch[8] = {};
      mm_mfma<8, 4>(xb + rt * 16 * XS, XS, p.wsW + 73728 + cb * 128 * 128, 128,
                    acch, l15, lg);
#pragma unroll
      for (int ct = 0; ct < 8; ++ct) {
        int c = ct * 16 + l15;
        float bia = p.b1[cb * 128 + c];
#pragma unroll
        for (int r = 0; r < 4; ++r)
          hb[(rt * 16 + lg * 4 + r) * XS + c] = (short)f2bf(fmaxf(acch[ct][r] + bia, 0.f));
      }
      __syncthreads();
      mm_mfma<8, 4>(hb + rt * 16 * XS, XS, p.wsW + 139264 + cb * 128, 512,
                    acc2, l15, lg);
      __syncthreads();
    }
    float s[4] = {}, sq[4] = {};
#pragma unroll
    for (int ct = 0; ct < 8; ++ct) {
      int c = ct * 16 + l15;
      float bia = p.b2[c];
#pragma unroll
      for (int r = 0; r < 4; ++r) {
        int row = rt * 16 + lg * 4 + r;
        acc2[ct][r] += bia + bf2f((unsigned short)xb[row * XS + c]);
        s[r] += acc2[ct][r]; sq[r] += acc2[ct][r] * acc2[ct][r];
      }
    }
    float mean[4], inv[4];
#pragma unroll
    for (int r = 0; r < 4; ++r) {
      float S = red16_add(s[r]), SQ = red16_add(sq[r]);
      mean[r] = S * (1.0f / CH);
      float var = fmaxf(SQ * (1.0f / CH) - mean[r] * mean[r], 0.f);
      inv[r] = rsqrtf(var + 1e-5f);
    }
#pragma unroll
    for (int ct = 0; ct < 8; ++ct) {
      int c = ct * 16 + l15;
      float g = p.ln2_g[c], bt = p.ln2_b[c];
#pragma unroll
      for (int r = 0; r < 4; ++r) {
        int row = rt * 16 + lg * 4 + r;
        xb[row * XS + c] = (short)f2bf((acc2[ct][r] - mean[r]) * inv[r] * g + bt);
      }
    }
  }
  __syncthreads();

  // ---- max-pool over K + LN(out) ----
  {
    float mx = -INFINITY;
#pragma unroll 8
    for (int r = 0; r < KNB; ++r) mx = fmaxf(mx, bf2f((unsigned short)xb[r * XS + t]));
    float s = mx, sq = mx * mx;
#pragma unroll
    for (int off = 1; off < 64; off <<= 1) {
      s  += __shfl_xor(s,  off, 64);
      sq += __shfl_xor(sq, off, 64);
    }
    if (lane == 0) { psum[rt][0] = s; psum[rt][1] = sq; }
    __syncthreads();
    float S = psum[0][0] + psum[1][0];
    float SQ = psum[0][1] + psum[1][1];
    float mean = S * (1.0f / CH);
    float var = fmaxf(SQ * (1.0f / CH) - mean * mean, 0.f);
    float inv = rsqrtf(var + 1e-5f);
    p.out[(size_t)BATCH * M_CTR * 3 + (size_t)cm * CH + t] =
        (mx - mean) * inv * p.out_g[t] + p.out_b[t];
  }
}

// ---------------------------------------------------------------------------
extern "C" void kernel_launch(void* const* d_in, const int* in_sizes, int n_in,
                              void* d_out, int out_size, void* d_ws, size_t ws_size,
                              hipStream_t stream) {
  const float* xyz     = (const float*)d_in[0];
  const float* feats   = (const float*)d_in[1];
  const float* W_in    = (const float*)d_in[2];
  const float* b_in    = (const float*)d_in[3];
  const float* ln_in_g = (const float*)d_in[4];
  const float* ln_in_b = (const float*)d_in[5];
  const float* W_pos   = (const float*)d_in[6];
  const float* b_pos   = (const float*)d_in[7];
  const float* Wq      = (const float*)d_in[8];
  const float* bq      = (const float*)d_in[9];
  const float* Wk      = (const float*)d_in[10];
  const float* bk      = (const float*)d_in[11];
  const float* Wv      = (const float*)d_in[12];
  const float* bv      = (const float*)d_in[13];
  const float* Wo      = (const float*)d_in[14];
  const float* bo      = (const float*)d_in[15];
  const float* ln1_g   = (const float*)d_in[16];
  const float* ln1_b   = (const float*)d_in[17];
  const float* W1      = (const float*)d_in[18];
  const float* b1      = (const float*)d_in[19];
  const float* W2      = (const float*)d_in[20];
  const float* b2      = (const float*)d_in[21];
  const float* ln2_g   = (const float*)d_in[22];
  const float* ln2_b   = (const float*)d_in[23];
  const float* out_g   = (const float*)d_in[24];
  const float* out_b   = (const float*)d_in[25];
  float* out = (float*)d_out;

  int* wsCtr = (int*)d_ws;                               // B*M ints (16 KB)
  int* wsRaw = wsCtr + BATCH * M_CTR;                    // B*M*K ints (512 KB)
  unsigned long long* candG =
      (unsigned long long*)(wsRaw + BATCH * M_CTR * KNB); // 16 u64 (8B-aligned)
  unsigned* tagG = (unsigned*)(candG + 2 * BATCH * FPSB); // 8 u32
  short* wsW = (short*)(tagG + BATCH * FPSB);             // 204800 bf16 weights

  init_sync<<<1, 64, 0, stream>>>(tagG);
  prep_kernel<<<(204800 + 255) / 256, 256, 0, stream>>>(W_in, Wq, Wk, Wv, Wo,
                                                        W1, W2, wsW);
  fps_kernel<<<BATCH * FPSB, 512, 0, stream>>>(xyz, wsCtr, out, candG, tagG);
  ballq_kernel<<<(BATCH * M_CTR) / 4, 256, 0, stream>>>(xyz, wsCtr, wsRaw);

  SAParams p{xyz, feats, b_in, ln_in_g, ln_in_b, W_pos, b_pos,
             bq, bk, bv, bo, ln1_g, ln1_b, b1, b2,
             ln2_g, ln2_b, out_g, out_b,
             wsW, wsCtr, wsRaw, out};
  sa_kernel<<<BATCH * M_CTR, 128, 0, stream>>>(p);
}

// Round 11
// 2920.075 us; speedup vs baseline: 1.6357x; 1.6357x over previous
//
#include <hip/hip_runtime.h>
#include <math.h>

#define N_PTS 8192
#define BATCH 2
#define M_CTR 2048
#define KNB   32
#define CIN   64
#define CH    128
#define NHEAD 8
#define DH    16

typedef __attribute__((ext_vector_type(4))) float f32x4;
typedef __attribute__((ext_vector_type(8))) short bf16x8;

// ---------------------------------------------------------------------------
// FPS v9: v5 algorithm (verified twice at 512thr/1876us) repartitioned to
// 1024 thr (8 pts/thread, 16 waves = 4/SIMD) for latency hiding of the
// serial reduce chain. u64 key (bits(d2)<<32)|~idx == (value desc, idx asc)
// -> exact numpy first-index argmax in any reduction order. Per-thread tree
// depth 3, DPP xor1/xor2/xor7/xor15 + ds_swizzle xor16 + shfl xor32
// (HW-verified lattice), 16-slot LDS tree, one barrier/iter (double-buffered
// candidates). Distances: exact f32 ops (no FMA contraction) matching the
// reference bitwise.
// ---------------------------------------------------------------------------
template<int CTRL>
__device__ __forceinline__ unsigned long long dpp_max_u64(unsigned long long k) {
  int lo = (int)(unsigned)k;
  int hi = (int)(k >> 32);
  int lo2 = __builtin_amdgcn_update_dpp(0, lo, CTRL, 0xF, 0xF, true);
  int hi2 = __builtin_amdgcn_update_dpp(0, hi, CTRL, 0xF, 0xF, true);
  unsigned long long o = ((unsigned long long)(unsigned)hi2 << 32) | (unsigned)lo2;
  return o > k ? o : k;
}

__device__ __forceinline__ unsigned long long swz16_max_u64(unsigned long long k) {
  int lo = (int)(unsigned)k;
  int hi = (int)(k >> 32);
  int lo2 = __builtin_amdgcn_ds_swizzle(lo, 0x401F);   // xor 16
  int hi2 = __builtin_amdgcn_ds_swizzle(hi, 0x401F);
  unsigned long long o = ((unsigned long long)(unsigned)hi2 << 32) | (unsigned)lo2;
  return o > k ? o : k;
}

__device__ __forceinline__ unsigned long long maxu64(unsigned long long a,
                                                     unsigned long long b) {
  return a > b ? a : b;
}

__global__ __launch_bounds__(1024, 1) void fps_kernel(const float* __restrict__ xyz,
                                                      int* __restrict__ ctrIdx,
                                                      float* __restrict__ outCtr) {
  __shared__ float4 sxyz[N_PTS];                    // 128 KB
  __shared__ int    cidx[M_CTR];                    // 8 KB
  __shared__ __align__(16) unsigned long long candK[2][16];

  const int b = blockIdx.x;
  const int t = threadIdx.x;
  const int lane = t & 63;
  const int w = t >> 6;                              // 0..15
  const float* xb = xyz + (size_t)b * N_PTS * 3;

  float px[8], py[8], pz[8], mind[8];
  unsigned lo8[8];
#pragma unroll
  for (int s = 0; s < 8; ++s) {
    int pt = t + s * 1024;
    float x = xb[pt * 3 + 0];
    float y = xb[pt * 3 + 1];
    float z = xb[pt * 3 + 2];
    px[s] = x; py[s] = y; pz[s] = z;
    mind[s] = INFINITY;
    lo8[s] = ~(unsigned)pt;
    sxyz[pt] = make_float4(x, y, z, 0.f);
  }
  __syncthreads();

  int last = 0;
  for (int m = 0; m < M_CTR; ++m) {
    if (t == 0) cidx[m] = last;
    float4 lp = sxyz[last];                          // uniform broadcast
#pragma unroll
    for (int s = 0; s < 8; ++s) {
      float dx = __fsub_rn(px[s], lp.x);
      float dy = __fsub_rn(py[s], lp.y);
      float dz = __fsub_rn(pz[s], lp.z);
      float d2 = __fadd_rn(__fadd_rn(__fmul_rn(dx, dx), __fmul_rn(dy, dy)),
                           __fmul_rn(dz, dz));
      mind[s] = fminf(mind[s], d2);
    }
    unsigned long long key[8];
#pragma unroll
    for (int s = 0; s < 8; ++s)
      key[s] = ((unsigned long long)__float_as_uint(mind[s]) << 32) | lo8[s];
    // per-thread tree max (depth 3)
#pragma unroll
    for (int i = 0; i < 4; ++i) key[i] = maxu64(key[i], key[i + 4]);
    key[0] = maxu64(key[0], key[2]);
    key[1] = maxu64(key[1], key[3]);
    unsigned long long k0 = maxu64(key[0], key[1]);
    // wave reduce: 4 DPP stages (VALU) + xor16 swizzle + xor32 shfl
    k0 = dpp_max_u64<0xB1>(k0);     // quad_perm xor1
    k0 = dpp_max_u64<0x4E>(k0);     // quad_perm xor2
    k0 = dpp_max_u64<0x141>(k0);    // row_half_mirror (xor7)
    k0 = dpp_max_u64<0x140>(k0);    // row_mirror (xor15)
    k0 = swz16_max_u64(k0);
    k0 = maxu64(k0, (unsigned long long)__shfl_xor((unsigned long long)k0, 32, 64));
    const int buf = m & 1;
    if (lane == 0) candK[buf][w] = k0;
    __syncthreads();
    // cross-wave: 16 candidates, b128 loads + tree (all threads, redundant)
    const ulonglong2* ck = (const ulonglong2*)&candK[buf][0];
    ulonglong2 c0v = ck[0], c1v = ck[1], c2v = ck[2], c3v = ck[3];
    ulonglong2 c4v = ck[4], c5v = ck[5], c6v = ck[6], c7v = ck[7];
    unsigned long long m0 = maxu64(c0v.x, c0v.y);
    unsigned long long m1 = maxu64(c1v.x, c1v.y);
    unsigned long long m2 = maxu64(c2v.x, c2v.y);
    unsigned long long m3 = maxu64(c3v.x, c3v.y);
    unsigned long long m4 = maxu64(c4v.x, c4v.y);
    unsigned long long m5 = maxu64(c5v.x, c5v.y);
    unsigned long long m6 = maxu64(c6v.x, c6v.y);
    unsigned long long m7 = maxu64(c7v.x, c7v.y);
    unsigned long long n0 = maxu64(maxu64(m0, m1), maxu64(m2, m3));
    unsigned long long n1 = maxu64(maxu64(m4, m5), maxu64(m6, m7));
    unsigned long long best = maxu64(n0, n1);
    last = (int)(~(unsigned)best);
  }
  __syncthreads();
  for (int m = t; m < M_CTR; m += 1024) {
    int ci = cidx[m];
    ctrIdx[b * M_CTR + m] = ci;
    float4 c = sxyz[ci];
    float* o = outCtr + (size_t)(b * M_CTR + m) * 3;
    o[0] = c.x; o[1] = c.y; o[2] = c.z;
  }
}

// ---------------------------------------------------------------------------
// Ball query (unchanged, passing since R1).
// ---------------------------------------------------------------------------
__global__ __launch_bounds__(256) void ballq_kernel(const float* __restrict__ xyz,
                                                    const int* __restrict__ ctrIdx,
                                                    int* __restrict__ rawIdx) {
  const int cm   = blockIdx.x * 4 + (threadIdx.x >> 6);
  const int lane = threadIdx.x & 63;
  const int b    = cm >> 11;
  const float* xb = xyz + (size_t)b * N_PTS * 3;
  const int ci = ctrIdx[cm];
  const float cx = xb[ci * 3 + 0], cy = xb[ci * 3 + 1], cz = xb[ci * 3 + 2];
  int* out = rawIdx + (size_t)cm * KNB;
  int have = 0;
  for (int base = 0; base < N_PTS; base += 64) {
    int pt = base + lane;
    float dx = __fsub_rn(cx, xb[pt * 3 + 0]);
    float dy = __fsub_rn(cy, xb[pt * 3 + 1]);
    float dz = __fsub_rn(cz, xb[pt * 3 + 2]);
    float d2 = __fadd_rn(__fadd_rn(__fmul_rn(dx, dx), __fmul_rn(dy, dy)),
                         __fmul_rn(dz, dz));
    bool hit = d2 < 0.25f;
    unsigned long long mask = __ballot(hit);
    if (hit) {
      int rank = have + __popcll(mask & ((1ull << lane) - 1ull));
      if (rank < KNB) out[rank] = pt;
    }
    have += __popcll(mask);
    if (have >= KNB) break;
  }
  if (lane < KNB && lane >= have) out[lane] = -1;
}

// ---------------------------------------------------------------------------
// Weight prep (unchanged): bf16 transposed weights Wt[c][k] in workspace.
// ---------------------------------------------------------------------------
__device__ __forceinline__ unsigned short f2bf(float f) {
  unsigned u = __float_as_uint(f);
  unsigned r = (u + 0x7FFFu + ((u >> 16) & 1u)) >> 16;   // RNE
  return (unsigned short)r;
}
__device__ __forceinline__ float bf2f(unsigned short s) {
  return __uint_as_float(((unsigned)s) << 16);
}

__global__ __launch_bounds__(256) void prep_kernel(const float* __restrict__ W_in,
    const float* __restrict__ Wq, const float* __restrict__ Wk,
    const float* __restrict__ Wv, const float* __restrict__ Wo,
    const float* __restrict__ W1, const float* __restrict__ W2,
    short* __restrict__ wsW) {
  int i = blockIdx.x * 256 + threadIdx.x;
  if (i >= 204800) return;
  const float* src; int K, C, off;
  if (i < 8192)        { src = W_in; K = 64;  C = 128; off = i; }
  else if (i < 24576)  { src = Wq;   K = 128; C = 128; off = i - 8192; }
  else if (i < 40960)  { src = Wk;   K = 128; C = 128; off = i - 24576; }
  else if (i < 57344)  { src = Wv;   K = 128; C = 128; off = i - 40960; }
  else if (i < 73728)  { src = Wo;   K = 128; C = 128; off = i - 57344; }
  else if (i < 139264) { src = W1;   K = 128; C = 512; off = i - 73728; }
  else                 { src = W2;   K = 512; C = 128; off = i - 139264; }
  int c = off / K, k = off - c * K;
  wsW[i] = (short)f2bf(src[(size_t)k * C + c]);
}

// ---------------------------------------------------------------------------
// Fused per-center transformer v3 (REVERTED to R6 version — passed twice,
// absmax 0.0625): MFMA bf16, 128 thr = 2 waves per center.
// ---------------------------------------------------------------------------
#define XS  136   // activation LDS row stride (shorts)
#define VTS 40    // vT row stride
#define PS  264   // P row stride

struct SAParams {
  const float* xyz; const float* feats;
  const float* b_in; const float* ln_in_g; const float* ln_in_b;
  const float* W_pos; const float* b_pos;
  const float* bq; const float* bk; const float* bv; const float* bo;
  const float* ln1_g; const float* ln1_b;
  const float* b1; const float* b2;
  const float* ln2_g; const float* ln2_b; const float* out_g; const float* out_b;
  const short* wsW;
  const int* ctrIdx; const int* rawIdx;
  float* out;
};

template<int C>
__device__ __forceinline__ float dppf(float v) {
  return __int_as_float(__builtin_amdgcn_update_dpp(0, __float_as_int(v), C, 0xF, 0xF, true));
}
__device__ __forceinline__ float red16_add(float v) {
  v += dppf<0xB1>(v);  v += dppf<0x4E>(v);
  v += dppf<0x141>(v); v += dppf<0x140>(v);
  return v;
}
__device__ __forceinline__ float red16_max(float v) {
  v = fmaxf(v, dppf<0xB1>(v));  v = fmaxf(v, dppf<0x4E>(v));
  v = fmaxf(v, dppf<0x141>(v)); v = fmaxf(v, dppf<0x140>(v));
  return v;
}

template<int NCT, int NKS>
__device__ __forceinline__ void mm_mfma(const short* __restrict__ albase, int lstr,
                                        const short* __restrict__ wt, int wK,
                                        f32x4 (&acc)[NCT], int l15, int lg) {
#pragma unroll
  for (int ks = 0; ks < NKS; ++ks) {
    bf16x8 a = *(const bf16x8*)(albase + l15 * lstr + ks * 32 + lg * 8);
#pragma unroll
    for (int ct = 0; ct < NCT; ++ct) {
      bf16x8 bf = *(const bf16x8*)(wt + (size_t)(ct * 16 + l15) * wK + ks * 32 + lg * 8);
      acc[ct] = __builtin_amdgcn_mfma_f32_16x16x32_bf16(a, bf, acc[ct], 0, 0, 0);
    }
  }
}

__global__ __launch_bounds__(128, 1) void sa_kernel(SAParams p) {
  __shared__ short sm[3 * 32 * XS + 128 * VTS + 32 * PS];
  __shared__ float nxs[32], nys[32], nzs[32];
  __shared__ int   nidx[32];
  __shared__ unsigned padmaskS;
  __shared__ float psum[2][2];

  short* const xb  = sm;
  short* const qb  = sm + 32 * XS;
  short* const kb  = sm + 2 * 32 * XS;
  short* const vT  = sm + 3 * 32 * XS;
  short* const Pb  = sm + 3 * 32 * XS + 128 * VTS;
  short* const fsb = Pb;
  short* const ob  = qb;
  short* const hb  = kb;

  const int t    = threadIdx.x;
  const int lane = t & 63;
  const int rt   = t >> 6;
  const int l15  = lane & 15;
  const int lg   = lane >> 4;
  const int cm   = blockIdx.x;
  const int b    = cm >> 11;
  const short* arow = 0;

  if (t < 32) {
    int raw = p.rawIdx[(size_t)cm * KNB + t];
    int ci  = p.ctrIdx[cm];
    int ni  = (raw < 0) ? ci : raw;
    nidx[t] = ni;
    const float* q = p.xyz + ((size_t)b * N_PTS + ni) * 3;
    nxs[t] = q[0]; nys[t] = q[1]; nzs[t] = q[2];
  }
  if (t < 64) {
    bool isPad = (t < 32) ? (p.rawIdx[(size_t)cm * KNB + t] < 0) : false;
    unsigned long long m = __ballot(isPad);
    if (t == 0) padmaskS = (unsigned)m;
  }
  __syncthreads();

  {
    int row = t >> 2;
    int cs  = (t & 3) * 16;
    const float* src = p.feats + ((size_t)b * N_PTS + nidx[row]) * CIN + cs;
    float4 f0 = *(const float4*)(src + 0);
    float4 f1 = *(const float4*)(src + 4);
    float4 f2 = *(const float4*)(src + 8);
    float4 f3 = *(const float4*)(src + 12);
    unsigned short u[16];
#pragma unroll
    for (int j = 0; j < 4; ++j) {
      u[j]      = f2bf((&f0.x)[j]); u[4 + j]  = f2bf((&f1.x)[j]);
      u[8 + j]  = f2bf((&f2.x)[j]); u[12 + j] = f2bf((&f3.x)[j]);
    }
    unsigned packed[8];
#pragma unroll
    for (int j = 0; j < 8; ++j) packed[j] = (unsigned)u[2 * j] | ((unsigned)u[2 * j + 1] << 16);
    uint4 w0 = make_uint4(packed[0], packed[1], packed[2], packed[3]);
    uint4 w1 = make_uint4(packed[4], packed[5], packed[6], packed[7]);
    *(uint4*)(fsb + row * 72 + cs)     = w0;
    *(uint4*)(fsb + row * 72 + cs + 8) = w1;
  }
  __syncthreads();

  const unsigned padmask = padmaskS;
  float rowxyz[3][4];
#pragma unroll
  for (int r = 0; r < 4; ++r) {
    int row = rt * 16 + lg * 4 + r;
    rowxyz[0][r] = nxs[row]; rowxyz[1][r] = nys[row]; rowxyz[2][r] = nzs[row];
  }

  // ---- in-proj + LN + relu + posenc -> xb ----
  {
    f32x4 acc[8] = {};
    mm_mfma<8, 2>(fsb + rt * 16 * 72, 72, p.wsW + 0, 64, acc, l15, lg);
    float s[4] = {}, sq[4] = {};
#pragma unroll
    for (int ct = 0; ct < 8; ++ct) {
      float bia = p.b_in[ct * 16 + l15];
#pragma unroll
      for (int r = 0; r < 4; ++r) {
        acc[ct][r] += bia;
        s[r] += acc[ct][r]; sq[r] += acc[ct][r] * acc[ct][r];
      }
    }
    float mean[4], inv[4];
#pragma unroll
    for (int r = 0; r < 4; ++r) {
      float S = red16_add(s[r]), SQ = red16_add(sq[r]);
      mean[r] = S * (1.0f / CH);
      float var = fmaxf(SQ * (1.0f / CH) - mean[r] * mean[r], 0.f);
      inv[r] = rsqrtf(var + 1e-5f);
    }
#pragma unroll
    for (int ct = 0; ct < 8; ++ct) {
      int c = ct * 16 + l15;
      float g  = p.ln_in_g[c], bt = p.ln_in_b[c];
      float w0 = p.W_pos[0 * CH + c], w1 = p.W_pos[1 * CH + c];
      float w2 = p.W_pos[2 * CH + c], bp = p.b_pos[c];
#pragma unroll
      for (int r = 0; r < 4; ++r) {
        int row = rt * 16 + lg * 4 + r;
        float h = (acc[ct][r] - mean[r]) * inv[r] * g + bt;
        h = fmaxf(h, 0.f);
        float pos = fmaf(rowxyz[0][r], w0, fmaf(rowxyz[1][r], w1,
                    fmaf(rowxyz[2][r], w2, bp)));
        xb[row * XS + c] = (short)f2bf(h + pos);
      }
    }
  }
  __syncthreads();

  // ---- q, k, v ----
  arow = xb + rt * 16 * XS;
  {
    f32x4 acc[8] = {};
    mm_mfma<8, 4>(arow, XS, p.wsW + 8192, 128, acc, l15, lg);
#pragma unroll
    for (int ct = 0; ct < 8; ++ct) {
      int c = ct * 16 + l15;
      float bia = p.bq[c];
#pragma unroll
      for (int r = 0; r < 4; ++r)
        qb[(rt * 16 + lg * 4 + r) * XS + c] = (short)f2bf((acc[ct][r] + bia) * 0.25f);
    }
  }
  {
    f32x4 acc[8] = {};
    mm_mfma<8, 4>(arow, XS, p.wsW + 24576, 128, acc, l15, lg);
#pragma unroll
    for (int ct = 0; ct < 8; ++ct) {
      int c = ct * 16 + l15;
      float bia = p.bk[c];
#pragma unroll
      for (int r = 0; r < 4; ++r)
        kb[(rt * 16 + lg * 4 + r) * XS + c] = (short)f2bf(acc[ct][r] + bia);
    }
  }
  {
    f32x4 acc[8] = {};
    mm_mfma<8, 4>(arow, XS, p.wsW + 40960, 128, acc, l15, lg);
#pragma unroll
    for (int ct = 0; ct < 8; ++ct) {
      int c = ct * 16 + l15;
      float bia = p.bv[c];
#pragma unroll
      for (int r = 0; r < 4; ++r)
        vT[c * VTS + rt * 16 + lg * 4 + r] = (short)f2bf(acc[ct][r] + bia);
    }
  }
  __syncthreads();

  // ---- scores + softmax -> Pb ----
  {
    bool pad0 = (padmask >> l15) & 1u;
    bool pad1 = (padmask >> (16 + l15)) & 1u;
    const bf16x8 z = {0, 0, 0, 0, 0, 0, 0, 0};
#pragma unroll
    for (int h = 0; h < NHEAD; ++h) {
      bf16x8 a = *(const bf16x8*)(qb + (rt * 16 + l15) * XS + h * DH + (lg & 1) * 8);
      if (lg >= 2) a = z;
      bf16x8 b0 = *(const bf16x8*)(kb + (l15) * XS + h * DH + (lg & 1) * 8);
      bf16x8 b1 = *(const bf16x8*)(kb + (16 + l15) * XS + h * DH + (lg & 1) * 8);
      f32x4 s0 = {}, s1 = {};
      s0 = __builtin_amdgcn_mfma_f32_16x16x32_bf16(a, b0, s0, 0, 0, 0);
      s1 = __builtin_amdgcn_mfma_f32_16x16x32_bf16(a, b1, s1, 0, 0, 0);
#pragma unroll
      for (int r = 0; r < 4; ++r) {
        float v0 = pad0 ? -1e9f : s0[r];
        float v1 = pad1 ? -1e9f : s1[r];
        float mx = red16_max(fmaxf(v0, v1));
        float e0 = __expf(v0 - mx), e1 = __expf(v1 - mx);
        float sum = red16_add(e0 + e1);
        float isum = 1.0f / sum;
        int row = rt * 16 + lg * 4 + r;
        Pb[row * PS + h * 32 + l15]      = (short)f2bf(e0 * isum);
        Pb[row * PS + h * 32 + 16 + l15] = (short)f2bf(e1 * isum);
      }
    }
  }
  __syncthreads();

  // ---- PV -> ob ----
  {
#pragma unroll
    for (int h = 0; h < NHEAD; ++h) {
      bf16x8 a  = *(const bf16x8*)(Pb + (rt * 16 + l15) * PS + h * 32 + lg * 8);
      bf16x8 bf = *(const bf16x8*)(vT + (h * DH + l15) * VTS + lg * 8);
      f32x4 o = {};
      o = __builtin_amdgcn_mfma_f32_16x16x32_bf16(a, bf, o, 0, 0, 0);
#pragma unroll
      for (int r = 0; r < 4; ++r)
        ob[(rt * 16 + lg * 4 + r) * XS + h * DH + l15] = (short)f2bf(o[r]);
    }
  }

  // ---- x = LN1(x + o@Wo + bo) (own rows only; no barrier needed) ----
  {
    f32x4 acc[8] = {};
    mm_mfma<8, 4>(ob + rt * 16 * XS, XS, p.wsW + 57344, 128, acc, l15, lg);
    float s[4] = {}, sq[4] = {};
#pragma unroll
    for (int ct = 0; ct < 8; ++ct) {
      int c = ct * 16 + l15;
      float bia = p.bo[c];
#pragma unroll
      for (int r = 0; r < 4; ++r) {
        int row = rt * 16 + lg * 4 + r;
        acc[ct][r] += bia + bf2f((unsigned short)xb[row * XS + c]);
        s[r] += acc[ct][r]; sq[r] += acc[ct][r] * acc[ct][r];
      }
    }
    float mean[4], inv[4];
#pragma unroll
    for (int r = 0; r < 4; ++r) {
      float S = red16_add(s[r]), SQ = red16_add(sq[r]);
      mean[r] = S * (1.0f / CH);
      float var = fmaxf(SQ * (1.0f / CH) - mean[r] * mean[r], 0.f);
      inv[r] = rsqrtf(var + 1e-5f);
    }
#pragma unroll
    for (int ct = 0; ct < 8; ++ct) {
      int c = ct * 16 + l15;
      float g = p.ln1_g[c], bt = p.ln1_b[c];
#pragma unroll
      for (int r = 0; r < 4; ++r) {
        int row = rt * 16 + lg * 4 + r;
        xb[row * XS + c] = (short)f2bf((acc[ct][r] - mean[r]) * inv[r] * g + bt);
      }
    }
  }

  // ---- FFN + LN2 ----
  {
    f32x4 acc2[8] = {};
#pragma unroll
    for (int cb = 0; cb < 4; ++cb) {
      f32x4 acch[8] = {};
      mm_mfma<8, 4>(xb + rt * 16 * XS, XS, p.wsW + 73728 + cb * 128 * 128, 128,
                    acch, l15, lg);
#pragma unroll
      for (int ct = 0; ct < 8; ++ct) {
        int c = ct * 16 + l15;
        float bia = p.b1[cb * 128 + c];
#pragma unroll
        for (int r = 0; r < 4; ++r)
          hb[(rt * 16 + lg * 4 + r) * XS + c] = (short)f2bf(fmaxf(acch[ct][r] + bia, 0.f));
      }
      __syncthreads();
      mm_mfma<8, 4>(hb + rt * 16 * XS, XS, p.wsW + 139264 + cb * 128, 512,
                    acc2, l15, lg);
      __syncthreads();
    }
    float s[4] = {}, sq[4] = {};
#pragma unroll
    for (int ct = 0; ct < 8; ++ct) {
      int c = ct * 16 + l15;
      float bia = p.b2[c];
#pragma unroll
      for (int r = 0; r < 4; ++r) {
        int row = rt * 16 + lg * 4 + r;
        acc2[ct][r] += bia + bf2f((unsigned short)xb[row * XS + c]);
        s[r] += acc2[ct][r]; sq[r] += acc2[ct][r] * acc2[ct][r];
      }
    }
    float mean[4], inv[4];
#pragma unroll
    for (int r = 0; r < 4; ++r) {
      float S = red16_add(s[r]), SQ = red16_add(sq[r]);
      mean[r] = S * (1.0f / CH);
      float var = fmaxf(SQ * (1.0f / CH) - mean[r] * mean[r], 0.f);
      inv[r] = rsqrtf(var + 1e-5f);
    }
#pragma unroll
    for (int ct = 0; ct < 8; ++ct) {
      int c = ct * 16 + l15;
      float g = p.ln2_g[c], bt = p.ln2_b[c];
#pragma unroll
      for (int r = 0; r < 4; ++r) {
        int row = rt * 16 + lg * 4 + r;
        xb[row * XS + c] = (short)f2bf((acc2[ct][r] - mean[r]) * inv[r] * g + bt);
      }
    }
  }
  __syncthreads();

  // ---- max-pool over K + LN(out) ----
  {
    float mx = -INFINITY;
#pragma unroll 8
    for (int r = 0; r < KNB; ++r) mx = fmaxf(mx, bf2f((unsigned short)xb[r * XS + t]));
    float s = mx, sq = mx * mx;
#pragma unroll
    for (int off = 1; off < 64; off <<= 1) {
      s  += __shfl_xor(s,  off, 64);
      sq += __shfl_xor(sq, off, 64);
    }
    if (lane == 0) { psum[rt][0] = s; psum[rt][1] = sq; }
    __syncthreads();
    float S = psum[0][0] + psum[1][0];
    float SQ = psum[0][1] + psum[1][1];
    float mean = S * (1.0f / CH);
    float var = fmaxf(SQ * (1.0f / CH) - mean * mean, 0.f);
    float inv = rsqrtf(var + 1e-5f);
    p.out[(size_t)BATCH * M_CTR * 3 + (size_t)cm * CH + t] =
        (mx - mean) * inv * p.out_g[t] + p.out_b[t];
  }
}

// ---------------------------------------------------------------------------
extern "C" void kernel_launch(void* const* d_in, const int* in_sizes, int n_in,
                              void* d_out, int out_size, void* d_ws, size_t ws_size,
                              hipStream_t stream) {
  const float* xyz     = (const float*)d_in[0];
  const float* feats   = (const float*)d_in[1];
  const float* W_in    = (const float*)d_in[2];
  const float* b_in    = (const float*)d_in[3];
  const float* ln_in_g = (const float*)d_in[4];
  const float* ln_in_b = (const float*)d_in[5];
  const float* W_pos   = (const float*)d_in[6];
  const float* b_pos   = (const float*)d_in[7];
  const float* Wq      = (const float*)d_in[8];
  const float* bq      = (const float*)d_in[9];
  const float* Wk      = (const float*)d_in[10];
  const float* bk      = (const float*)d_in[11];
  const float* Wv      = (const float*)d_in[12];
  const float* bv      = (const float*)d_in[13];
  const float* Wo      = (const float*)d_in[14];
  const float* bo      = (const float*)d_in[15];
  const float* ln1_g   = (const float*)d_in[16];
  const float* ln1_b   = (const float*)d_in[17];
  const float* W1      = (const float*)d_in[18];
  const float* b1      = (const float*)d_in[19];
  const float* W2      = (const float*)d_in[20];
  const float* b2      = (const float*)d_in[21];
  const float* ln2_g   = (const float*)d_in[22];
  const float* ln2_b   = (const float*)d_in[23];
  const float* out_g   = (const float*)d_in[24];
  const float* out_b   = (const float*)d_in[25];
  float* out = (float*)d_out;

  int* wsCtr = (int*)d_ws;                       // B*M ints
  int* wsRaw = wsCtr + BATCH * M_CTR;            // B*M*K ints
  short* wsW = (short*)(wsRaw + BATCH * M_CTR * KNB);  // 204800 bf16 weights

  prep_kernel<<<(204800 + 255) / 256, 256, 0, stream>>>(W_in, Wq, Wk, Wv, Wo,
                                                        W1, W2, wsW);
  fps_kernel<<<BATCH, 1024, 0, stream>>>(xyz, wsCtr, out);
  ballq_kernel<<<(BATCH * M_CTR) / 4, 256, 0, stream>>>(xyz, wsCtr, wsRaw);

  SAParams p{xyz, feats, b_in, ln_in_g, ln_in_b, W_pos, b_pos,
             bq, bk, bv, bo, ln1_g, ln1_b, b1, b2,
             ln2_g, ln2_b, out_g, out_b,
             wsW, wsCtr, wsRaw, out};
  sa_kernel<<<BATCH * M_CTR, 128, 0, stream>>>(p);
}

// Round 12
// 2501.269 us; speedup vs baseline: 1.9096x; 1.1674x over previous
//
#include <hip/hip_runtime.h>
#include <math.h>

#define N_PTS 8192
#define BATCH 2
#define M_CTR 2048
#define KNB   32
#define CIN   64
#define CH    128
#define NHEAD 8
#define DH    16

typedef __attribute__((ext_vector_type(4))) float f32x4;
typedef __attribute__((ext_vector_type(2))) float f32x2;
typedef __attribute__((ext_vector_type(8))) short bf16x8;

// ---------------------------------------------------------------------------
// FPS v10: v5 structure (512 thr, 16 pts/thread, best measured 1876us x2)
// with the dist loop in packed FP32 (v_pk_add_f32 / v_pk_mul_f32, VOP3P).
// Packed ops = two independent IEEE-RN f32 ops -> bitwise identical to the
// scalar reference arithmetic; a-b computed as a+(-b) (exact). Key/tree/DPP
// butterfly (xor1/xor2/xor7/xor15 + swz16 + shfl32) + 8-slot candK protocol
// byte-identical to v5.
// ---------------------------------------------------------------------------
__device__ __forceinline__ f32x2 pk_add(f32x2 a, f32x2 b) {
  f32x2 d;
  asm("v_pk_add_f32 %0, %1, %2" : "=v"(d) : "v"(a), "v"(b));
  return d;
}
__device__ __forceinline__ f32x2 pk_mul(f32x2 a, f32x2 b) {
  f32x2 d;
  asm("v_pk_mul_f32 %0, %1, %2" : "=v"(d) : "v"(a), "v"(b));
  return d;
}

template<int CTRL>
__device__ __forceinline__ unsigned long long dpp_max_u64(unsigned long long k) {
  int lo = (int)(unsigned)k;
  int hi = (int)(k >> 32);
  int lo2 = __builtin_amdgcn_update_dpp(0, lo, CTRL, 0xF, 0xF, true);
  int hi2 = __builtin_amdgcn_update_dpp(0, hi, CTRL, 0xF, 0xF, true);
  unsigned long long o = ((unsigned long long)(unsigned)hi2 << 32) | (unsigned)lo2;
  return o > k ? o : k;
}

__device__ __forceinline__ unsigned long long swz16_max_u64(unsigned long long k) {
  int lo = (int)(unsigned)k;
  int hi = (int)(k >> 32);
  int lo2 = __builtin_amdgcn_ds_swizzle(lo, 0x401F);   // xor 16
  int hi2 = __builtin_amdgcn_ds_swizzle(hi, 0x401F);
  unsigned long long o = ((unsigned long long)(unsigned)hi2 << 32) | (unsigned)lo2;
  return o > k ? o : k;
}

__device__ __forceinline__ unsigned long long maxu64(unsigned long long a,
                                                     unsigned long long b) {
  return a > b ? a : b;
}

__global__ __launch_bounds__(512, 1) void fps_kernel(const float* __restrict__ xyz,
                                                     int* __restrict__ ctrIdx,
                                                     float* __restrict__ outCtr) {
  __shared__ float4 sxyz[N_PTS];
  __shared__ int    cidx[M_CTR];
  __shared__ __align__(16) unsigned long long candK[2][8];

  const int b = blockIdx.x;
  const int t = threadIdx.x;
  const int lane = t & 63;
  const int w = t >> 6;
  const float* xb = xyz + (size_t)b * N_PTS * 3;

  f32x2 px2[8], py2[8], pz2[8], mind2[8];
#pragma unroll
  for (int s = 0; s < 8; ++s) {
    int p0 = t + (2 * s) * 512;
    int p1 = t + (2 * s + 1) * 512;
    float x0 = xb[p0 * 3 + 0], y0 = xb[p0 * 3 + 1], z0 = xb[p0 * 3 + 2];
    float x1 = xb[p1 * 3 + 0], y1 = xb[p1 * 3 + 1], z1 = xb[p1 * 3 + 2];
    px2[s] = f32x2{x0, x1}; py2[s] = f32x2{y0, y1}; pz2[s] = f32x2{z0, z1};
    mind2[s] = f32x2{INFINITY, INFINITY};
    sxyz[p0] = make_float4(x0, y0, z0, 0.f);
    sxyz[p1] = make_float4(x1, y1, z1, 0.f);
  }
  unsigned lo16[16];
#pragma unroll
  for (int s = 0; s < 16; ++s) lo16[s] = ~(unsigned)(t + s * 512);
  __syncthreads();

  int last = 0;
  for (int m = 0; m < M_CTR; ++m) {
    if (t == 0) cidx[m] = last;
    float4 lp = sxyz[last];
    const f32x2 nx2 = f32x2{-lp.x, -lp.x};
    const f32x2 ny2 = f32x2{-lp.y, -lp.y};
    const f32x2 nz2 = f32x2{-lp.z, -lp.z};
#pragma unroll
    for (int s = 0; s < 8; ++s) {
      f32x2 dx = pk_add(px2[s], nx2);       // px - lp.x (exact: a+(-b))
      f32x2 dy = pk_add(py2[s], ny2);
      f32x2 dz = pk_add(pz2[s], nz2);
      f32x2 xx = pk_mul(dx, dx);
      f32x2 yy = pk_mul(dy, dy);
      f32x2 zz = pk_mul(dz, dz);
      f32x2 d2 = pk_add(pk_add(xx, yy), zz); // ((dx2+dy2)+dz2) order preserved
      mind2[s].x = fminf(mind2[s].x, d2.x);
      mind2[s].y = fminf(mind2[s].y, d2.y);
    }
    unsigned long long key[16];
#pragma unroll
    for (int s = 0; s < 8; ++s) {
      key[2 * s]     = ((unsigned long long)__float_as_uint(mind2[s].x) << 32) | lo16[2 * s];
      key[2 * s + 1] = ((unsigned long long)__float_as_uint(mind2[s].y) << 32) | lo16[2 * s + 1];
    }
#pragma unroll
    for (int i = 0; i < 8; ++i) key[i] = maxu64(key[i], key[i + 8]);
#pragma unroll
    for (int i = 0; i < 4; ++i) key[i] = maxu64(key[i], key[i + 4]);
    key[0] = maxu64(key[0], key[2]);
    key[1] = maxu64(key[1], key[3]);
    unsigned long long k0 = maxu64(key[0], key[1]);
    k0 = dpp_max_u64<0xB1>(k0);     // quad_perm xor1
    k0 = dpp_max_u64<0x4E>(k0);     // quad_perm xor2
    k0 = dpp_max_u64<0x141>(k0);    // row_half_mirror (xor7)
    k0 = dpp_max_u64<0x140>(k0);    // row_mirror (xor15)
    k0 = swz16_max_u64(k0);
    k0 = maxu64(k0, (unsigned long long)__shfl_xor((unsigned long long)k0, 32, 64));
    const int buf = m & 1;
    if (lane == 0) candK[buf][w] = k0;
    __syncthreads();
    const ulonglong2* ck = (const ulonglong2*)&candK[buf][0];
    ulonglong2 c0v = ck[0], c1v = ck[1], c2v = ck[2], c3v = ck[3];
    unsigned long long m0 = maxu64(c0v.x, c0v.y);
    unsigned long long m1 = maxu64(c1v.x, c1v.y);
    unsigned long long m2 = maxu64(c2v.x, c2v.y);
    unsigned long long m3 = maxu64(c3v.x, c3v.y);
    unsigned long long best = maxu64(maxu64(m0, m1), maxu64(m2, m3));
    last = (int)(~(unsigned)best);
  }
  __syncthreads();
  for (int m = t; m < M_CTR; m += 512) {
    int ci = cidx[m];
    ctrIdx[b * M_CTR + m] = ci;
    float4 c = sxyz[ci];
    float* o = outCtr + (size_t)(b * M_CTR + m) * 3;
    o[0] = c.x; o[1] = c.y; o[2] = c.z;
  }
}

// ---------------------------------------------------------------------------
// Ball query (unchanged, passing since R1).
// ---------------------------------------------------------------------------
__global__ __launch_bounds__(256) void ballq_kernel(const float* __restrict__ xyz,
                                                    const int* __restrict__ ctrIdx,
                                                    int* __restrict__ rawIdx) {
  const int cm   = blockIdx.x * 4 + (threadIdx.x >> 6);
  const int lane = threadIdx.x & 63;
  const int b    = cm >> 11;
  const float* xb = xyz + (size_t)b * N_PTS * 3;
  const int ci = ctrIdx[cm];
  const float cx = xb[ci * 3 + 0], cy = xb[ci * 3 + 1], cz = xb[ci * 3 + 2];
  int* out = rawIdx + (size_t)cm * KNB;
  int have = 0;
  for (int base = 0; base < N_PTS; base += 64) {
    int pt = base + lane;
    float dx = __fsub_rn(cx, xb[pt * 3 + 0]);
    float dy = __fsub_rn(cy, xb[pt * 3 + 1]);
    float dz = __fsub_rn(cz, xb[pt * 3 + 2]);
    float d2 = __fadd_rn(__fadd_rn(__fmul_rn(dx, dx), __fmul_rn(dy, dy)),
                         __fmul_rn(dz, dz));
    bool hit = d2 < 0.25f;
    unsigned long long mask = __ballot(hit);
    if (hit) {
      int rank = have + __popcll(mask & ((1ull << lane) - 1ull));
      if (rank < KNB) out[rank] = pt;
    }
    have += __popcll(mask);
    if (have >= KNB) break;
  }
  if (lane < KNB && lane >= have) out[lane] = -1;
}

// ---------------------------------------------------------------------------
// Weight prep (unchanged): bf16 transposed weights Wt[c][k] in workspace.
// ---------------------------------------------------------------------------
__device__ __forceinline__ unsigned short f2bf(float f) {
  unsigned u = __float_as_uint(f);
  unsigned r = (u + 0x7FFFu + ((u >> 16) & 1u)) >> 16;   // RNE
  return (unsigned short)r;
}
__device__ __forceinline__ float bf2f(unsigned short s) {
  return __uint_as_float(((unsigned)s) << 16);
}

__global__ __launch_bounds__(256) void prep_kernel(const float* __restrict__ W_in,
    const float* __restrict__ Wq, const float* __restrict__ Wk,
    const float* __restrict__ Wv, const float* __restrict__ Wo,
    const float* __restrict__ W1, const float* __restrict__ W2,
    short* __restrict__ wsW) {
  int i = blockIdx.x * 256 + threadIdx.x;
  if (i >= 204800) return;
  const float* src; int K, C, off;
  if (i < 8192)        { src = W_in; K = 64;  C = 128; off = i; }
  else if (i < 24576)  { src = Wq;   K = 128; C = 128; off = i - 8192; }
  else if (i < 40960)  { src = Wk;   K = 128; C = 128; off = i - 24576; }
  else if (i < 57344)  { src = Wv;   K = 128; C = 128; off = i - 40960; }
  else if (i < 73728)  { src = Wo;   K = 128; C = 128; off = i - 57344; }
  else if (i < 139264) { src = W1;   K = 128; C = 512; off = i - 73728; }
  else                 { src = W2;   K = 512; C = 128; off = i - 139264; }
  int c = off / K, k = off - c * K;
  wsW[i] = (short)f2bf(src[(size_t)k * C + c]);
}

// ---------------------------------------------------------------------------
// Fused per-center transformer v3 (unchanged — passed 3x, absmax 0.0625):
// MFMA bf16, 128 thr = 2 waves per center.
// ---------------------------------------------------------------------------
#define XS  136   // activation LDS row stride (shorts)
#define VTS 40    // vT row stride
#define PS  264   // P row stride

struct SAParams {
  const float* xyz; const float* feats;
  const float* b_in; const float* ln_in_g; const float* ln_in_b;
  const float* W_pos; const float* b_pos;
  const float* bq; const float* bk; const float* bv; const float* bo;
  const float* ln1_g; const float* ln1_b;
  const float* b1; const float* b2;
  const float* ln2_g; const float* ln2_b; const float* out_g; const float* out_b;
  const short* wsW;
  const int* ctrIdx; const int* rawIdx;
  float* out;
};

template<int C>
__device__ __forceinline__ float dppf(float v) {
  return __int_as_float(__builtin_amdgcn_update_dpp(0, __float_as_int(v), C, 0xF, 0xF, true));
}
__device__ __forceinline__ float red16_add(float v) {
  v += dppf<0xB1>(v);  v += dppf<0x4E>(v);
  v += dppf<0x141>(v); v += dppf<0x140>(v);
  return v;
}
__device__ __forceinline__ float red16_max(float v) {
  v = fmaxf(v, dppf<0xB1>(v));  v = fmaxf(v, dppf<0x4E>(v));
  v = fmaxf(v, dppf<0x141>(v)); v = fmaxf(v, dppf<0x140>(v));
  return v;
}

template<int NCT, int NKS>
__device__ __forceinline__ void mm_mfma(const short* __restrict__ albase, int lstr,
                                        const short* __restrict__ wt, int wK,
                                        f32x4 (&acc)[NCT], int l15, int lg) {
#pragma unroll
  for (int ks = 0; ks < NKS; ++ks) {
    bf16x8 a = *(const bf16x8*)(albase + l15 * lstr + ks * 32 + lg * 8);
#pragma unroll
    for (int ct = 0; ct < NCT; ++ct) {
      bf16x8 bf = *(const bf16x8*)(wt + (size_t)(ct * 16 + l15) * wK + ks * 32 + lg * 8);
      acc[ct] = __builtin_amdgcn_mfma_f32_16x16x32_bf16(a, bf, acc[ct], 0, 0, 0);
    }
  }
}

__global__ __launch_bounds__(128, 1) void sa_kernel(SAParams p) {
  __shared__ short sm[3 * 32 * XS + 128 * VTS + 32 * PS];
  __shared__ float nxs[32], nys[32], nzs[32];
  __shared__ int   nidx[32];
  __shared__ unsigned padmaskS;
  __shared__ float psum[2][2];

  short* const xb  = sm;
  short* const qb  = sm + 32 * XS;
  short* const kb  = sm + 2 * 32 * XS;
  short* const vT  = sm + 3 * 32 * XS;
  short* const Pb  = sm + 3 * 32 * XS + 128 * VTS;
  short* const fsb = Pb;
  short* const ob  = qb;
  short* const hb  = kb;

  const int t    = threadIdx.x;
  const int lane = t & 63;
  const int rt   = t >> 6;
  const int l15  = lane & 15;
  const int lg   = lane >> 4;
  const int cm   = blockIdx.x;
  const int b    = cm >> 11;
  const short* arow = 0;

  if (t < 32) {
    int raw = p.rawIdx[(size_t)cm * KNB + t];
    int ci  = p.ctrIdx[cm];
    int ni  = (raw < 0) ? ci : raw;
    nidx[t] = ni;
    const float* q = p.xyz + ((size_t)b * N_PTS + ni) * 3;
    nxs[t] = q[0]; nys[t] = q[1]; nzs[t] = q[2];
  }
  if (t < 64) {
    bool isPad = (t < 32) ? (p.rawIdx[(size_t)cm * KNB + t] < 0) : false;
    unsigned long long m = __ballot(isPad);
    if (t == 0) padmaskS = (unsigned)m;
  }
  __syncthreads();

  {
    int row = t >> 2;
    int cs  = (t & 3) * 16;
    const float* src = p.feats + ((size_t)b * N_PTS + nidx[row]) * CIN + cs;
    float4 f0 = *(const float4*)(src + 0);
    float4 f1 = *(const float4*)(src + 4);
    float4 f2 = *(const float4*)(src + 8);
    float4 f3 = *(const float4*)(src + 12);
    unsigned short u[16];
#pragma unroll
    for (int j = 0; j < 4; ++j) {
      u[j]      = f2bf((&f0.x)[j]); u[4 + j]  = f2bf((&f1.x)[j]);
      u[8 + j]  = f2bf((&f2.x)[j]); u[12 + j] = f2bf((&f3.x)[j]);
    }
    unsigned packed[8];
#pragma unroll
    for (int j = 0; j < 8; ++j) packed[j] = (unsigned)u[2 * j] | ((unsigned)u[2 * j + 1] << 16);
    uint4 w0 = make_uint4(packed[0], packed[1], packed[2], packed[3]);
    uint4 w1 = make_uint4(packed[4], packed[5], packed[6], packed[7]);
    *(uint4*)(fsb + row * 72 + cs)     = w0;
    *(uint4*)(fsb + row * 72 + cs + 8) = w1;
  }
  __syncthreads();

  const unsigned padmask = padmaskS;
  float rowxyz[3][4];
#pragma unroll
  for (int r = 0; r < 4; ++r) {
    int row = rt * 16 + lg * 4 + r;
    rowxyz[0][r] = nxs[row]; rowxyz[1][r] = nys[row]; rowxyz[2][r] = nzs[row];
  }

  // ---- in-proj + LN + relu + posenc -> xb ----
  {
    f32x4 acc[8] = {};
    mm_mfma<8, 2>(fsb + rt * 16 * 72, 72, p.wsW + 0, 64, acc, l15, lg);
    float s[4] = {}, sq[4] = {};
#pragma unroll
    for (int ct = 0; ct < 8; ++ct) {
      float bia = p.b_in[ct * 16 + l15];
#pragma unroll
      for (int r = 0; r < 4; ++r) {
        acc[ct][r] += bia;
        s[r] += acc[ct][r]; sq[r] += acc[ct][r] * acc[ct][r];
      }
    }
    float mean[4], inv[4];
#pragma unroll
    for (int r = 0; r < 4; ++r) {
      float S = red16_add(s[r]), SQ = red16_add(sq[r]);
      mean[r] = S * (1.0f / CH);
      float var = fmaxf(SQ * (1.0f / CH) - mean[r] * mean[r], 0.f);
      inv[r] = rsqrtf(var + 1e-5f);
    }
#pragma unroll
    for (int ct = 0; ct < 8; ++ct) {
      int c = ct * 16 + l15;
      float g  = p.ln_in_g[c], bt = p.ln_in_b[c];
      float w0 = p.W_pos[0 * CH + c], w1 = p.W_pos[1 * CH + c];
      float w2 = p.W_pos[2 * CH + c], bp = p.b_pos[c];
#pragma unroll
      for (int r = 0; r < 4; ++r) {
        int row = rt * 16 + lg * 4 + r;
        float h = (acc[ct][r] - mean[r]) * inv[r] * g + bt;
        h = fmaxf(h, 0.f);
        float pos = fmaf(rowxyz[0][r], w0, fmaf(rowxyz[1][r], w1,
                    fmaf(rowxyz[2][r], w2, bp)));
        xb[row * XS + c] = (short)f2bf(h + pos);
      }
    }
  }
  __syncthreads();

  // ---- q, k, v ----
  arow = xb + rt * 16 * XS;
  {
    f32x4 acc[8] = {};
    mm_mfma<8, 4>(arow, XS, p.wsW + 8192, 128, acc, l15, lg);
#pragma unroll
    for (int ct = 0; ct < 8; ++ct) {
      int c = ct * 16 + l15;
      float bia = p.bq[c];
#pragma unroll
      for (int r = 0; r < 4; ++r)
        qb[(rt * 16 + lg * 4 + r) * XS + c] = (short)f2bf((acc[ct][r] + bia) * 0.25f);
    }
  }
  {
    f32x4 acc[8] = {};
    mm_mfma<8, 4>(arow, XS, p.wsW + 24576, 128, acc, l15, lg);
#pragma unroll
    for (int ct = 0; ct < 8; ++ct) {
      int c = ct * 16 + l15;
      float bia = p.bk[c];
#pragma unroll
      for (int r = 0; r < 4; ++r)
        kb[(rt * 16 + lg * 4 + r) * XS + c] = (short)f2bf(acc[ct][r] + bia);
    }
  }
  {
    f32x4 acc[8] = {};
    mm_mfma<8, 4>(arow, XS, p.wsW + 40960, 128, acc, l15, lg);
#pragma unroll
    for (int ct = 0; ct < 8; ++ct) {
      int c = ct * 16 + l15;
      float bia = p.bv[c];
#pragma unroll
      for (int r = 0; r < 4; ++r)
        vT[c * VTS + rt * 16 + lg * 4 + r] = (short)f2bf(acc[ct][r] + bia);
    }
  }
  __syncthreads();

  // ---- scores + softmax -> Pb ----
  {
    bool pad0 = (padmask >> l15) & 1u;
    bool pad1 = (padmask >> (16 + l15)) & 1u;
    const bf16x8 z = {0, 0, 0, 0, 0, 0, 0, 0};
#pragma unroll
    for (int h = 0; h < NHEAD; ++h) {
      bf16x8 a = *(const bf16x8*)(qb + (rt * 16 + l15) * XS + h * DH + (lg & 1) * 8);
      if (lg >= 2) a = z;
      bf16x8 b0 = *(const bf16x8*)(kb + (l15) * XS + h * DH + (lg & 1) * 8);
      bf16x8 b1 = *(const bf16x8*)(kb + (16 + l15) * XS + h * DH + (lg & 1) * 8);
      f32x4 s0 = {}, s1 = {};
      s0 = __builtin_amdgcn_mfma_f32_16x16x32_bf16(a, b0, s0, 0, 0, 0);
      s1 = __builtin_amdgcn_mfma_f32_16x16x32_bf16(a, b1, s1, 0, 0, 0);
#pragma unroll
      for (int r = 0; r < 4; ++r) {
        float v0 = pad0 ? -1e9f : s0[r];
        float v1 = pad1 ? -1e9f : s1[r];
        float mx = red16_max(fmaxf(v0, v1));
        float e0 = __expf(v0 - mx), e1 = __expf(v1 - mx);
        float sum = red16_add(e0 + e1);
        float isum = 1.0f / sum;
        int row = rt * 16 + lg * 4 + r;
        Pb[row * PS + h * 32 + l15]      = (short)f2bf(e0 * isum);
        Pb[row * PS + h * 32 + 16 + l15] = (short)f2bf(e1 * isum);
      }
    }
  }
  __syncthreads();

  // ---- PV -> ob ----
  {
#pragma unroll
    for (int h = 0; h < NHEAD; ++h) {
      bf16x8 a  = *(const bf16x8*)(Pb + (rt * 16 + l15) * PS + h * 32 + lg * 8);
      bf16x8 bf = *(const bf16x8*)(vT + (h * DH + l15) * VTS + lg * 8);
      f32x4 o = {};
      o = __builtin_amdgcn_mfma_f32_16x16x32_bf16(a, bf, o, 0, 0, 0);
#pragma unroll
      for (int r = 0; r < 4; ++r)
        ob[(rt * 16 + lg * 4 + r) * XS + h * DH + l15] = (short)f2bf(o[r]);
    }
  }

  // ---- x = LN1(x + o@Wo + bo) (own rows only; no barrier needed) ----
  {
    f32x4 acc[8] = {};
    mm_mfma<8, 4>(ob + rt * 16 * XS, XS, p.wsW + 57344, 128, acc, l15, lg);
    float s[4] = {}, sq[4] = {};
#pragma unroll
    for (int ct = 0; ct < 8; ++ct) {
      int c = ct * 16 + l15;
      float bia = p.bo[c];
#pragma unroll
      for (int r = 0; r < 4; ++r) {
        int row = rt * 16 + lg * 4 + r;
        acc[ct][r] += bia + bf2f((unsigned short)xb[row * XS + c]);
        s[r] += acc[ct][r]; sq[r] += acc[ct][r] * acc[ct][r];
      }
    }
    float mean[4], inv[4];
#pragma unroll
    for (int r = 0; r < 4; ++r) {
      float S = red16_add(s[r]), SQ = red16_add(sq[r]);
      mean[r] = S * (1.0f / CH);
      float var = fmaxf(SQ * (1.0f / CH) - mean[r] * mean[r], 0.f);
      inv[r] = rsqrtf(var + 1e-5f);
    }
#pragma unroll
    for (int ct = 0; ct < 8; ++ct) {
      int c = ct * 16 + l15;
      float g = p.ln1_g[c], bt = p.ln1_b[c];
#pragma unroll
      for (int r = 0; r < 4; ++r) {
        int row = rt * 16 + lg * 4 + r;
        xb[row * XS + c] = (short)f2bf((acc[ct][r] - mean[r]) * inv[r] * g + bt);
      }
    }
  }

  // ---- FFN + LN2 ----
  {
    f32x4 acc2[8] = {};
#pragma unroll
    for (int cb = 0; cb < 4; ++cb) {
      f32x4 acch[8] = {};
      mm_mfma<8, 4>(xb + rt * 16 * XS, XS, p.wsW + 73728 + cb * 128 * 128, 128,
                    acch, l15, lg);
#pragma unroll
      for (int ct = 0; ct < 8; ++ct) {
        int c = ct * 16 + l15;
        float bia = p.b1[cb * 128 + c];
#pragma unroll
        for (int r = 0; r < 4; ++r)
          hb[(rt * 16 + lg * 4 + r) * XS + c] = (short)f2bf(fmaxf(acch[ct][r] + bia, 0.f));
      }
      __syncthreads();
      mm_mfma<8, 4>(hb + rt * 16 * XS, XS, p.wsW + 139264 + cb * 128, 512,
                    acc2, l15, lg);
      __syncthreads();
    }
    float s[4] = {}, sq[4] = {};
#pragma unroll
    for (int ct = 0; ct < 8; ++ct) {
      int c = ct * 16 + l15;
      float bia = p.b2[c];
#pragma unroll
      for (int r = 0; r < 4; ++r) {
        int row = rt * 16 + lg * 4 + r;
        acc2[ct][r] += bia + bf2f((unsigned short)xb[row * XS + c]);
        s[r] += acc2[ct][r]; sq[r] += acc2[ct][r] * acc2[ct][r];
      }
    }
    float mean[4], inv[4];
#pragma unroll
    for (int r = 0; r < 4; ++r) {
      float S = red16_add(s[r]), SQ = red16_add(sq[r]);
      mean[r] = S * (1.0f / CH);
      float var = fmaxf(SQ * (1.0f / CH) - mean[r] * mean[r], 0.f);
      inv[r] = rsqrtf(var + 1e-5f);
    }
#pragma unroll
    for (int ct = 0; ct < 8; ++ct) {
      int c = ct * 16 + l15;
      float g = p.ln2_g[c], bt = p.ln2_b[c];
#pragma unroll
      for (int r = 0; r < 4; ++r) {
        int row = rt * 16 + lg * 4 + r;
        xb[row * XS + c] = (short)f2bf((acc2[ct][r] - mean[r]) * inv[r] * g + bt);
      }
    }
  }
  __syncthreads();

  // ---- max-pool over K + LN(out) ----
  {
    float mx = -INFINITY;
#pragma unroll 8
    for (int r = 0; r < KNB; ++r) mx = fmaxf(mx, bf2f((unsigned short)xb[r * XS + t]));
    float s = mx, sq = mx * mx;
#pragma unroll
    for (int off = 1; off < 64; off <<= 1) {
      s  += __shfl_xor(s,  off, 64);
      sq += __shfl_xor(sq, off, 64);
    }
    if (lane == 0) { psum[rt][0] = s; psum[rt][1] = sq; }
    __syncthreads();
    float S = psum[0][0] + psum[1][0];
    float SQ = psum[0][1] + psum[1][1];
    float mean = S * (1.0f / CH);
    float var = fmaxf(SQ * (1.0f / CH) - mean * mean, 0.f);
    float inv = rsqrtf(var + 1e-5f);
    p.out[(size_t)BATCH * M_CTR * 3 + (size_t)cm * CH + t] =
        (mx - mean) * inv * p.out_g[t] + p.out_b[t];
  }
}

// ---------------------------------------------------------------------------
extern "C" void kernel_launch(void* const* d_in, const int* in_sizes, int n_in,
                              void* d_out, int out_size, void* d_ws, size_t ws_size,
                              hipStream_t stream) {
  const float* xyz     = (const float*)d_in[0];
  const float* feats   = (const float*)d_in[1];
  const float* W_in    = (const float*)d_in[2];
  const float* b_in    = (const float*)d_in[3];
  const float* ln_in_g = (const float*)d_in[4];
  const float* ln_in_b = (const float*)d_in[5];
  const float* W_pos   = (const float*)d_in[6];
  const float* b_pos   = (const float*)d_in[7];
  const float* Wq      = (const float*)d_in[8];
  const float* bq      = (const float*)d_in[9];
  const float* Wk      = (const float*)d_in[10];
  const float* bk      = (const float*)d_in[11];
  const float* Wv      = (const float*)d_in[12];
  const float* bv      = (const float*)d_in[13];
  const float* Wo      = (const float*)d_in[14];
  const float* bo      = (const float*)d_in[15];
  const float* ln1_g   = (const float*)d_in[16];
  const float* ln1_b   = (const float*)d_in[17];
  const float* W1      = (const float*)d_in[18];
  const float* b1      = (const float*)d_in[19];
  const float* W2      = (const float*)d_in[20];
  const float* b2      = (const float*)d_in[21];
  const float* ln2_g   = (const float*)d_in[22];
  const float* ln2_b   = (const float*)d_in[23];
  const float* out_g   = (const float*)d_in[24];
  const float* out_b   = (const float*)d_in[25];
  float* out = (float*)d_out;

  int* wsCtr = (int*)d_ws;                       // B*M ints
  int* wsRaw = wsCtr + BATCH * M_CTR;            // B*M*K ints
  short* wsW = (short*)(wsRaw + BATCH * M_CTR * KNB);  // 204800 bf16 weights

  prep_kernel<<<(204800 + 255) / 256, 256, 0, stream>>>(W_in, Wq, Wk, Wv, Wo,
                                                        W1, W2, wsW);
  fps_kernel<<<BATCH, 512, 0, stream>>>(xyz, wsCtr, out);
  ballq_kernel<<<(BATCH * M_CTR) / 4, 256, 0, stream>>>(xyz, wsCtr, wsRaw);

  SAParams p{xyz, feats, b_in, ln_in_g, ln_in_b, W_pos, b_pos,
             bq, bk, bv, bo, ln1_g, ln1_b, b1, b2,
             ln2_g, ln2_b, out_g, out_b,
             wsW, wsCtr, wsRaw, out};
  sa_kernel<<<BATCH * M_CTR, 128, 0, stream>>>(p);
}

// Round 13
// 2351.751 us; speedup vs baseline: 2.0310x; 1.0636x over previous
//
#include <hip/hip_runtime.h>
#include <math.h>

#define N_PTS 8192
#define BATCH 2
#define M_CTR 2048
#define KNB   32
#define CIN   64
#define CH    128
#define NHEAD 8
#define DH    16

typedef __attribute__((ext_vector_type(4))) float f32x4;
typedef __attribute__((ext_vector_type(8))) short bf16x8;

// ---------------------------------------------------------------------------
// FPS v5 (best measured: 1876-1887 us, passing 2x): 512 thr, 16 pts/thread
// in regs. u64 key (bits(d2)<<32)|~idx == (value desc, index asc) -> exact
// numpy first-index argmax in any reduction order. Per-thread tree (depth 4),
// DPP xor1/xor2/xor7/xor15 + ds_swizzle xor16 + shfl xor32 (verified lattice),
// 8-slot LDS tree, one barrier/iter (double-buffered candidates).
// Distances: exact f32 ops (no FMA contraction), matching reference bitwise.
// Local-optimum evidence (7 variants): cutting ops or adding waves regresses.
// ---------------------------------------------------------------------------
template<int CTRL>
__device__ __forceinline__ unsigned long long dpp_max_u64(unsigned long long k) {
  int lo = (int)(unsigned)k;
  int hi = (int)(k >> 32);
  int lo2 = __builtin_amdgcn_update_dpp(0, lo, CTRL, 0xF, 0xF, true);
  int hi2 = __builtin_amdgcn_update_dpp(0, hi, CTRL, 0xF, 0xF, true);
  unsigned long long o = ((unsigned long long)(unsigned)hi2 << 32) | (unsigned)lo2;
  return o > k ? o : k;
}

__device__ __forceinline__ unsigned long long swz16_max_u64(unsigned long long k) {
  int lo = (int)(unsigned)k;
  int hi = (int)(k >> 32);
  int lo2 = __builtin_amdgcn_ds_swizzle(lo, 0x401F);   // xor 16
  int hi2 = __builtin_amdgcn_ds_swizzle(hi, 0x401F);
  unsigned long long o = ((unsigned long long)(unsigned)hi2 << 32) | (unsigned)lo2;
  return o > k ? o : k;
}

__device__ __forceinline__ unsigned long long maxu64(unsigned long long a,
                                                     unsigned long long b) {
  return a > b ? a : b;
}

__global__ __launch_bounds__(512, 1) void fps_kernel(const float* __restrict__ xyz,
                                                     int* __restrict__ ctrIdx,
                                                     float* __restrict__ outCtr) {
  __shared__ float4 sxyz[N_PTS];
  __shared__ int    cidx[M_CTR];
  __shared__ __align__(16) unsigned long long candK[2][8];

  const int b = blockIdx.x;
  const int t = threadIdx.x;
  const int lane = t & 63;
  const int w = t >> 6;
  const float* xb = xyz + (size_t)b * N_PTS * 3;

  float px[16], py[16], pz[16], mind[16];
#pragma unroll
  for (int s = 0; s < 16; ++s) {
    int pt = t + s * 512;
    float x = xb[pt * 3 + 0];
    float y = xb[pt * 3 + 1];
    float z = xb[pt * 3 + 2];
    px[s] = x; py[s] = y; pz[s] = z;
    mind[s] = INFINITY;
    sxyz[pt] = make_float4(x, y, z, 0.f);
  }
  unsigned lo16[16];
#pragma unroll
  for (int s = 0; s < 16; ++s) lo16[s] = ~(unsigned)(t + s * 512);
  __syncthreads();

  int last = 0;
  for (int m = 0; m < M_CTR; ++m) {
    if (t == 0) cidx[m] = last;
    float4 lp = sxyz[last];
#pragma unroll
    for (int s = 0; s < 16; ++s) {
      float dx = __fsub_rn(px[s], lp.x);
      float dy = __fsub_rn(py[s], lp.y);
      float dz = __fsub_rn(pz[s], lp.z);
      float d2 = __fadd_rn(__fadd_rn(__fmul_rn(dx, dx), __fmul_rn(dy, dy)),
                           __fmul_rn(dz, dz));
      mind[s] = fminf(mind[s], d2);
    }
    unsigned long long key[16];
#pragma unroll
    for (int s = 0; s < 16; ++s)
      key[s] = ((unsigned long long)__float_as_uint(mind[s]) << 32) | lo16[s];
#pragma unroll
    for (int i = 0; i < 8; ++i) key[i] = maxu64(key[i], key[i + 8]);
#pragma unroll
    for (int i = 0; i < 4; ++i) key[i] = maxu64(key[i], key[i + 4]);
    key[0] = maxu64(key[0], key[2]);
    key[1] = maxu64(key[1], key[3]);
    unsigned long long k0 = maxu64(key[0], key[1]);
    k0 = dpp_max_u64<0xB1>(k0);     // quad_perm xor1
    k0 = dpp_max_u64<0x4E>(k0);     // quad_perm xor2
    k0 = dpp_max_u64<0x141>(k0);    // row_half_mirror (xor7)
    k0 = dpp_max_u64<0x140>(k0);    // row_mirror (xor15)
    k0 = swz16_max_u64(k0);
    k0 = maxu64(k0, (unsigned long long)__shfl_xor((unsigned long long)k0, 32, 64));
    const int buf = m & 1;
    if (lane == 0) candK[buf][w] = k0;
    __syncthreads();
    const ulonglong2* ck = (const ulonglong2*)&candK[buf][0];
    ulonglong2 c0v = ck[0], c1v = ck[1], c2v = ck[2], c3v = ck[3];
    unsigned long long m0 = maxu64(c0v.x, c0v.y);
    unsigned long long m1 = maxu64(c1v.x, c1v.y);
    unsigned long long m2 = maxu64(c2v.x, c2v.y);
    unsigned long long m3 = maxu64(c3v.x, c3v.y);
    unsigned long long best = maxu64(maxu64(m0, m1), maxu64(m2, m3));
    last = (int)(~(unsigned)best);
  }
  __syncthreads();
  for (int m = t; m < M_CTR; m += 512) {
    int ci = cidx[m];
    ctrIdx[b * M_CTR + m] = ci;
    float4 c = sxyz[ci];
    float* o = outCtr + (size_t)(b * M_CTR + m) * 3;
    o[0] = c.x; o[1] = c.y; o[2] = c.z;
  }
}

// ---------------------------------------------------------------------------
// Ball query (unchanged, passing since R1).
// ---------------------------------------------------------------------------
__global__ __launch_bounds__(256) void ballq_kernel(const float* __restrict__ xyz,
                                                    const int* __restrict__ ctrIdx,
                                                    int* __restrict__ rawIdx) {
  const int cm   = blockIdx.x * 4 + (threadIdx.x >> 6);
  const int lane = threadIdx.x & 63;
  const int b    = cm >> 11;
  const float* xb = xyz + (size_t)b * N_PTS * 3;
  const int ci = ctrIdx[cm];
  const float cx = xb[ci * 3 + 0], cy = xb[ci * 3 + 1], cz = xb[ci * 3 + 2];
  int* out = rawIdx + (size_t)cm * KNB;
  int have = 0;
  for (int base = 0; base < N_PTS; base += 64) {
    int pt = base + lane;
    float dx = __fsub_rn(cx, xb[pt * 3 + 0]);
    float dy = __fsub_rn(cy, xb[pt * 3 + 1]);
    float dz = __fsub_rn(cz, xb[pt * 3 + 2]);
    float d2 = __fadd_rn(__fadd_rn(__fmul_rn(dx, dx), __fmul_rn(dy, dy)),
                         __fmul_rn(dz, dz));
    bool hit = d2 < 0.25f;
    unsigned long long mask = __ballot(hit);
    if (hit) {
      int rank = have + __popcll(mask & ((1ull << lane) - 1ull));
      if (rank < KNB) out[rank] = pt;
    }
    have += __popcll(mask);
    if (have >= KNB) break;
  }
  if (lane < KNB && lane >= have) out[lane] = -1;
}

// ---------------------------------------------------------------------------
// Weight prep (unchanged): bf16 transposed weights Wt[c][k] in workspace.
// ---------------------------------------------------------------------------
__device__ __forceinline__ unsigned short f2bf(float f) {
  unsigned u = __float_as_uint(f);
  unsigned r = (u + 0x7FFFu + ((u >> 16) & 1u)) >> 16;   // RNE
  return (unsigned short)r;
}
__device__ __forceinline__ float bf2f(unsigned short s) {
  return __uint_as_float(((unsigned)s) << 16);
}

__global__ __launch_bounds__(256) void prep_kernel(const float* __restrict__ W_in,
    const float* __restrict__ Wq, const float* __restrict__ Wk,
    const float* __restrict__ Wv, const float* __restrict__ Wo,
    const float* __restrict__ W1, const float* __restrict__ W2,
    short* __restrict__ wsW) {
  int i = blockIdx.x * 256 + threadIdx.x;
  if (i >= 204800) return;
  const float* src; int K, C, off;
  if (i < 8192)        { src = W_in; K = 64;  C = 128; off = i; }
  else if (i < 24576)  { src = Wq;   K = 128; C = 128; off = i - 8192; }
  else if (i < 40960)  { src = Wk;   K = 128; C = 128; off = i - 24576; }
  else if (i < 57344)  { src = Wv;   K = 128; C = 128; off = i - 40960; }
  else if (i < 73728)  { src = Wo;   K = 128; C = 128; off = i - 57344; }
  else if (i < 139264) { src = W1;   K = 128; C = 512; off = i - 73728; }
  else                 { src = W2;   K = 512; C = 128; off = i - 139264; }
  int c = off / K, k = off - c * K;
  wsW[i] = (short)f2bf(src[(size_t)k * C + c]);
}

// ---------------------------------------------------------------------------
// Fused per-center transformer v3 (passed 3x, absmax 0.0625): MFMA bf16,
// 128 thr = 2 waves per center.
// ---------------------------------------------------------------------------
#define XS  136   // activation LDS row stride (shorts)
#define VTS 40    // vT row stride
#define PS  264   // P row stride

struct SAParams {
  const float* xyz; const float* feats;
  const float* b_in; const float* ln_in_g; const float* ln_in_b;
  const float* W_pos; const float* b_pos;
  const float* bq; const float* bk; const float* bv; const float* bo;
  const float* ln1_g; const float* ln1_b;
  const float* b1; const float* b2;
  const float* ln2_g; const float* ln2_b; const float* out_g; const float* out_b;
  const short* wsW;
  const int* ctrIdx; const int* rawIdx;
  float* out;
};

template<int C>
__device__ __forceinline__ float dppf(float v) {
  return __int_as_float(__builtin_amdgcn_update_dpp(0, __float_as_int(v), C, 0xF, 0xF, true));
}
__device__ __forceinline__ float red16_add(float v) {
  v += dppf<0xB1>(v);  v += dppf<0x4E>(v);
  v += dppf<0x141>(v); v += dppf<0x140>(v);
  return v;
}
__device__ __forceinline__ float red16_max(float v) {
  v = fmaxf(v, dppf<0xB1>(v));  v = fmaxf(v, dppf<0x4E>(v));
  v = fmaxf(v, dppf<0x141>(v)); v = fmaxf(v, dppf<0x140>(v));
  return v;
}

template<int NCT, int NKS>
__device__ __forceinline__ void mm_mfma(const short* __restrict__ albase, int lstr,
                                        const short* __restrict__ wt, int wK,
                                        f32x4 (&acc)[NCT], int l15, int lg) {
#pragma unroll
  for (int ks = 0; ks < NKS; ++ks) {
    bf16x8 a = *(const bf16x8*)(albase + l15 * lstr + ks * 32 + lg * 8);
#pragma unroll
    for (int ct = 0; ct < NCT; ++ct) {
      bf16x8 bf = *(const bf16x8*)(wt + (size_t)(ct * 16 + l15) * wK + ks * 32 + lg * 8);
      acc[ct] = __builtin_amdgcn_mfma_f32_16x16x32_bf16(a, bf, acc[ct], 0, 0, 0);
    }
  }
}

__global__ __launch_bounds__(128, 1) void sa_kernel(SAParams p) {
  __shared__ short sm[3 * 32 * XS + 128 * VTS + 32 * PS];
  __shared__ float nxs[32], nys[32], nzs[32];
  __shared__ int   nidx[32];
  __shared__ unsigned padmaskS;
  __shared__ float psum[2][2];

  short* const xb  = sm;
  short* const qb  = sm + 32 * XS;
  short* const kb  = sm + 2 * 32 * XS;
  short* const vT  = sm + 3 * 32 * XS;
  short* const Pb  = sm + 3 * 32 * XS + 128 * VTS;
  short* const fsb = Pb;
  short* const ob  = qb;
  short* const hb  = kb;

  const int t    = threadIdx.x;
  const int lane = t & 63;
  const int rt   = t >> 6;
  const int l15  = lane & 15;
  const int lg   = lane >> 4;
  const int cm   = blockIdx.x;
  const int b    = cm >> 11;
  const short* arow = 0;

  if (t < 32) {
    int raw = p.rawIdx[(size_t)cm * KNB + t];
    int ci  = p.ctrIdx[cm];
    int ni  = (raw < 0) ? ci : raw;
    nidx[t] = ni;
    const float* q = p.xyz + ((size_t)b * N_PTS + ni) * 3;
    nxs[t] = q[0]; nys[t] = q[1]; nzs[t] = q[2];
  }
  if (t < 64) {
    bool isPad = (t < 32) ? (p.rawIdx[(size_t)cm * KNB + t] < 0) : false;
    unsigned long long m = __ballot(isPad);
    if (t == 0) padmaskS = (unsigned)m;
  }
  __syncthreads();

  {
    int row = t >> 2;
    int cs  = (t & 3) * 16;
    const float* src = p.feats + ((size_t)b * N_PTS + nidx[row]) * CIN + cs;
    float4 f0 = *(const float4*)(src + 0);
    float4 f1 = *(const float4*)(src + 4);
    float4 f2 = *(const float4*)(src + 8);
    float4 f3 = *(const float4*)(src + 12);
    unsigned short u[16];
#pragma unroll
    for (int j = 0; j < 4; ++j) {
      u[j]      = f2bf((&f0.x)[j]); u[4 + j]  = f2bf((&f1.x)[j]);
      u[8 + j]  = f2bf((&f2.x)[j]); u[12 + j] = f2bf((&f3.x)[j]);
    }
    unsigned packed[8];
#pragma unroll
    for (int j = 0; j < 8; ++j) packed[j] = (unsigned)u[2 * j] | ((unsigned)u[2 * j + 1] << 16);
    uint4 w0 = make_uint4(packed[0], packed[1], packed[2], packed[3]);
    uint4 w1 = make_uint4(packed[4], packed[5], packed[6], packed[7]);
    *(uint4*)(fsb + row * 72 + cs)     = w0;
    *(uint4*)(fsb + row * 72 + cs + 8) = w1;
  }
  __syncthreads();

  const unsigned padmask = padmaskS;
  float rowxyz[3][4];
#pragma unroll
  for (int r = 0; r < 4; ++r) {
    int row = rt * 16 + lg * 4 + r;
    rowxyz[0][r] = nxs[row]; rowxyz[1][r] = nys[row]; rowxyz[2][r] = nzs[row];
  }

  // ---- in-proj + LN + relu + posenc -> xb ----
  {
    f32x4 acc[8] = {};
    mm_mfma<8, 2>(fsb + rt * 16 * 72, 72, p.wsW + 0, 64, acc, l15, lg);
    float s[4] = {}, sq[4] = {};
#pragma unroll
    for (int ct = 0; ct < 8; ++ct) {
      float bia = p.b_in[ct * 16 + l15];
#pragma unroll
      for (int r = 0; r < 4; ++r) {
        acc[ct][r] += bia;
        s[r] += acc[ct][r]; sq[r] += acc[ct][r] * acc[ct][r];
      }
    }
    float mean[4], inv[4];
#pragma unroll
    for (int r = 0; r < 4; ++r) {
      float S = red16_add(s[r]), SQ = red16_add(sq[r]);
      mean[r] = S * (1.0f / CH);
      float var = fmaxf(SQ * (1.0f / CH) - mean[r] * mean[r], 0.f);
      inv[r] = rsqrtf(var + 1e-5f);
    }
#pragma unroll
    for (int ct = 0; ct < 8; ++ct) {
      int c = ct * 16 + l15;
      float g  = p.ln_in_g[c], bt = p.ln_in_b[c];
      float w0 = p.W_pos[0 * CH + c], w1 = p.W_pos[1 * CH + c];
      float w2 = p.W_pos[2 * CH + c], bp = p.b_pos[c];
#pragma unroll
      for (int r = 0; r < 4; ++r) {
        int row = rt * 16 + lg * 4 + r;
        float h = (acc[ct][r] - mean[r]) * inv[r] * g + bt;
        h = fmaxf(h, 0.f);
        float pos = fmaf(rowxyz[0][r], w0, fmaf(rowxyz[1][r], w1,
                    fmaf(rowxyz[2][r], w2, bp)));
        xb[row * XS + c] = (short)f2bf(h + pos);
      }
    }
  }
  __syncthreads();

  // ---- q, k, v ----
  arow = xb + rt * 16 * XS;
  {
    f32x4 acc[8] = {};
    mm_mfma<8, 4>(arow, XS, p.wsW + 8192, 128, acc, l15, lg);
#pragma unroll
    for (int ct = 0; ct < 8; ++ct) {
      int c = ct * 16 + l15;
      float bia = p.bq[c];
#pragma unroll
      for (int r = 0; r < 4; ++r)
        qb[(rt * 16 + lg * 4 + r) * XS + c] = (short)f2bf((acc[ct][r] + bia) * 0.25f);
    }
  }
  {
    f32x4 acc[8] = {};
    mm_mfma<8, 4>(arow, XS, p.wsW + 24576, 128, acc, l15, lg);
#pragma unroll
    for (int ct = 0; ct < 8; ++ct) {
      int c = ct * 16 + l15;
      float bia = p.bk[c];
#pragma unroll
      for (int r = 0; r < 4; ++r)
        kb[(rt * 16 + lg * 4 + r) * XS + c] = (short)f2bf(acc[ct][r] + bia);
    }
  }
  {
    f32x4 acc[8] = {};
    mm_mfma<8, 4>(arow, XS, p.wsW + 40960, 128, acc, l15, lg);
#pragma unroll
    for (int ct = 0; ct < 8; ++ct) {
      int c = ct * 16 + l15;
      float bia = p.bv[c];
#pragma unroll
      for (int r = 0; r < 4; ++r)
        vT[c * VTS + rt * 16 + lg * 4 + r] = (short)f2bf(acc[ct][r] + bia);
    }
  }
  __syncthreads();

  // ---- scores + softmax -> Pb ----
  {
    bool pad0 = (padmask >> l15) & 1u;
    bool pad1 = (padmask >> (16 + l15)) & 1u;
    const bf16x8 z = {0, 0, 0, 0, 0, 0, 0, 0};
#pragma unroll
    for (int h = 0; h < NHEAD; ++h) {
      bf16x8 a = *(const bf16x8*)(qb + (rt * 16 + l15) * XS + h * DH + (lg & 1) * 8);
      if (lg >= 2) a = z;
      bf16x8 b0 = *(const bf16x8*)(kb + (l15) * XS + h * DH + (lg & 1) * 8);
      bf16x8 b1 = *(const bf16x8*)(kb + (16 + l15) * XS + h * DH + (lg & 1) * 8);
      f32x4 s0 = {}, s1 = {};
      s0 = __builtin_amdgcn_mfma_f32_16x16x32_bf16(a, b0, s0, 0, 0, 0);
      s1 = __builtin_amdgcn_mfma_f32_16x16x32_bf16(a, b1, s1, 0, 0, 0);
#pragma unroll
      for (int r = 0; r < 4; ++r) {
        float v0 = pad0 ? -1e9f : s0[r];
        float v1 = pad1 ? -1e9f : s1[r];
        float mx = red16_max(fmaxf(v0, v1));
        float e0 = __expf(v0 - mx), e1 = __expf(v1 - mx);
        float sum = red16_add(e0 + e1);
        float isum = 1.0f / sum;
        int row = rt * 16 + lg * 4 + r;
        Pb[row * PS + h * 32 + l15]      = (short)f2bf(e0 * isum);
        Pb[row * PS + h * 32 + 16 + l15] = (short)f2bf(e1 * isum);
      }
    }
  }
  __syncthreads();

  // ---- PV -> ob ----
  {
#pragma unroll
    for (int h = 0; h < NHEAD; ++h) {
      bf16x8 a  = *(const bf16x8*)(Pb + (rt * 16 + l15) * PS + h * 32 + lg * 8);
      bf16x8 bf = *(const bf16x8*)(vT + (h * DH + l15) * VTS + lg * 8);
      f32x4 o = {};
      o = __builtin_amdgcn_mfma_f32_16x16x32_bf16(a, bf, o, 0, 0, 0);
#pragma unroll
      for (int r = 0; r < 4; ++r)
        ob[(rt * 16 + lg * 4 + r) * XS + h * DH + l15] = (short)f2bf(o[r]);
    }
  }

  // ---- x = LN1(x + o@Wo + bo) (own rows only; no barrier needed) ----
  {
    f32x4 acc[8] = {};
    mm_mfma<8, 4>(ob + rt * 16 * XS, XS, p.wsW + 57344, 128, acc, l15, lg);
    float s[4] = {}, sq[4] = {};
#pragma unroll
    for (int ct = 0; ct < 8; ++ct) {
      int c = ct * 16 + l15;
      float bia = p.bo[c];
#pragma unroll
      for (int r = 0; r < 4; ++r) {
        int row = rt * 16 + lg * 4 + r;
        acc[ct][r] += bia + bf2f((unsigned short)xb[row * XS + c]);
        s[r] += acc[ct][r]; sq[r] += acc[ct][r] * acc[ct][r];
      }
    }
    float mean[4], inv[4];
#pragma unroll
    for (int r = 0; r < 4; ++r) {
      float S = red16_add(s[r]), SQ = red16_add(sq[r]);
      mean[r] = S * (1.0f / CH);
      float var = fmaxf(SQ * (1.0f / CH) - mean[r] * mean[r], 0.f);
      inv[r] = rsqrtf(var + 1e-5f);
    }
#pragma unroll
    for (int ct = 0; ct < 8; ++ct) {
      int c = ct * 16 + l15;
      float g = p.ln1_g[c], bt = p.ln1_b[c];
#pragma unroll
      for (int r = 0; r < 4; ++r) {
        int row = rt * 16 + lg * 4 + r;
        xb[row * XS + c] = (short)f2bf((acc[ct][r] - mean[r]) * inv[r] * g + bt);
      }
    }
  }

  // ---- FFN + LN2 ----
  {
    f32x4 acc2[8] = {};
#pragma unroll
    for (int cb = 0; cb < 4; ++cb) {
      f32x4 acch[8] = {};
      mm_mfma<8, 4>(xb + rt * 16 * XS, XS, p.wsW + 73728 + cb * 128 * 128, 128,
                    acch, l15, lg);
#pragma unroll
      for (int ct = 0; ct < 8; ++ct) {
        int c = ct * 16 + l15;
        float bia = p.b1[cb * 128 + c];
#pragma unroll
        for (int r = 0; r < 4; ++r)
          hb[(rt * 16 + lg * 4 + r) * XS + c] = (short)f2bf(fmaxf(acch[ct][r] + bia, 0.f));
      }
      __syncthreads();
      mm_mfma<8, 4>(hb + rt * 16 * XS, XS, p.wsW + 139264 + cb * 128, 512,
                    acc2, l15, lg);
      __syncthreads();
    }
    float s[4] = {}, sq[4] = {};
#pragma unroll
    for (int ct = 0; ct < 8; ++ct) {
      int c = ct * 16 + l15;
      float bia = p.b2[c];
#pragma unroll
      for (int r = 0; r < 4; ++r) {
        int row = rt * 16 + lg * 4 + r;
        acc2[ct][r] += bia + bf2f((unsigned short)xb[row * XS + c]);
        s[r] += acc2[ct][r]; sq[r] += acc2[ct][r] * acc2[ct][r];
      }
    }
    float mean[4], inv[4];
#pragma unroll
    for (int r = 0; r < 4; ++r) {
      float S = red16_add(s[r]), SQ = red16_add(sq[r]);
      mean[r] = S * (1.0f / CH);
      float var = fmaxf(SQ * (1.0f / CH) - mean[r] * mean[r], 0.f);
      inv[r] = rsqrtf(var + 1e-5f);
    }
#pragma unroll
    for (int ct = 0; ct < 8; ++ct) {
      int c = ct * 16 + l15;
      float g = p.ln2_g[c], bt = p.ln2_b[c];
#pragma unroll
      for (int r = 0; r < 4; ++r) {
        int row = rt * 16 + lg * 4 + r;
        xb[row * XS + c] = (short)f2bf((acc2[ct][r] - mean[r]) * inv[r] * g + bt);
      }
    }
  }
  __syncthreads();

  // ---- max-pool over K + LN(out) ----
  {
    float mx = -INFINITY;
#pragma unroll 8
    for (int r = 0; r < KNB; ++r) mx = fmaxf(mx, bf2f((unsigned short)xb[r * XS + t]));
    float s = mx, sq = mx * mx;
#pragma unroll
    for (int off = 1; off < 64; off <<= 1) {
      s  += __shfl_xor(s,  off, 64);
      sq += __shfl_xor(sq, off, 64);
    }
    if (lane == 0) { psum[rt][0] = s; psum[rt][1] = sq; }
    __syncthreads();
    float S = psum[0][0] + psum[1][0];
    float SQ = psum[0][1] + psum[1][1];
    float mean = S * (1.0f / CH);
    float var = fmaxf(SQ * (1.0f / CH) - mean * mean, 0.f);
    float inv = rsqrtf(var + 1e-5f);
    p.out[(size_t)BATCH * M_CTR * 3 + (size_t)cm * CH + t] =
        (mx - mean) * inv * p.out_g[t] + p.out_b[t];
  }
}

// ---------------------------------------------------------------------------
extern "C" void kernel_launch(void* const* d_in, const int* in_sizes, int n_in,
                              void* d_out, int out_size, void* d_ws, size_t ws_size,
                              hipStream_t stream) {
  const float* xyz     = (const float*)d_in[0];
  const float* feats   = (const float*)d_in[1];
  const float* W_in    = (const float*)d_in[2];
  const float* b_in    = (const float*)d_in[3];
  const float* ln_in_g = (const float*)d_in[4];
  const float* ln_in_b = (const float*)d_in[5];
  const float* W_pos   = (const float*)d_in[6];
  const float* b_pos   = (const float*)d_in[7];
  const float* Wq      = (const float*)d_in[8];
  const float* bq      = (const float*)d_in[9];
  const float* Wk      = (const float*)d_in[10];
  const float* bk      = (const float*)d_in[11];
  const float* Wv      = (const float*)d_in[12];
  const float* bv      = (const float*)d_in[13];
  const float* Wo      = (const float*)d_in[14];
  const float* bo      = (const float*)d_in[15];
  const float* ln1_g   = (const float*)d_in[16];
  const float* ln1_b   = (const float*)d_in[17];
  const float* W1      = (const float*)d_in[18];
  const float* b1      = (const float*)d_in[19];
  const float* W2      = (const float*)d_in[20];
  const float* b2      = (const float*)d_in[21];
  const float* ln2_g   = (const float*)d_in[22];
  const float* ln2_b   = (const float*)d_in[23];
  const float* out_g   = (const float*)d_in[24];
  const float* out_b   = (const float*)d_in[25];
  float* out = (float*)d_out;

  int* wsCtr = (int*)d_ws;                       // B*M ints
  int* wsRaw = wsCtr + BATCH * M_CTR;            // B*M*K ints
  short* wsW = (short*)(wsRaw + BATCH * M_CTR * KNB);  // 204800 bf16 weights

  prep_kernel<<<(204800 + 255) / 256, 256, 0, stream>>>(W_in, Wq, Wk, Wv, Wo,
                                                        W1, W2, wsW);
  fps_kernel<<<BATCH, 512, 0, stream>>>(xyz, wsCtr, out);
  ballq_kernel<<<(BATCH * M_CTR) / 4, 256, 0, stream>>>(xyz, wsCtr, wsRaw);

  SAParams p{xyz, feats, b_in, ln_in_g, ln_in_b, W_pos, b_pos,
             bq, bk, bv, bo, ln1_g, ln1_b, b1, b2,
             ln2_g, ln2_b, out_g, out_b,
             wsW, wsCtr, wsRaw, out};
  sa_kernel<<<BATCH * M_CTR, 128, 0, stream>>>(p);
}